// Round 5
// baseline (625.442 us; speedup 1.0000x reference)
//
#include <hip/hip_runtime.h>
#include <hip/hip_bf16.h>
#include <math.h>

__device__ __forceinline__ float silu(float a) {
    return a / (1.f + __expf(-a));
}

// ---------------------------------------------------------------------------
// Kernel 1: per-token MLPs (q/k/v), RoPE(q,k), xm MLP -> v_x, build V' [T,20].
// 4 tokens per block (128 threads). Grid: B * T/4 = 2048 blocks.
// ---------------------------------------------------------------------------
__global__ __launch_bounds__(128) void qkv_kernel(
    const float* __restrict__ x, const float* __restrict__ h,
    const float* __restrict__ qw1, const float* __restrict__ qb1,
    const float* __restrict__ qw2, const float* __restrict__ qb2,
    const float* __restrict__ kw1, const float* __restrict__ kb1,
    const float* __restrict__ kw2, const float* __restrict__ kb2,
    const float* __restrict__ vw1, const float* __restrict__ vb1,
    const float* __restrict__ vw2, const float* __restrict__ vb2,
    const float* __restrict__ xmw1, const float* __restrict__ xmb1,
    const float* __restrict__ xmw2, const float* __restrict__ xmb2,
    float* __restrict__ q_ws, float* __restrict__ k_ws,
    float* __restrict__ vext_ws)
{
    const int blk = blockIdx.x;
    const int b  = blk >> 9;            // T/4 = 512 blocks per batch
    const int t0 = (blk & 511) << 2;
    const int tid = threadIdx.x;

    __shared__ __align__(16) float hm[256][4];
    __shared__ __align__(16) float hid[128][4];
    __shared__ __align__(16) float vout[128][4];
    __shared__ __align__(16) float tmp[128][4];
    __shared__ float vx[8][4];

    // load h_m: h is [B, D, T] fp32; 4 consecutive t -> one float4 per d
    #pragma unroll
    for (int dd = 0; dd < 2; dd++) {
        int d = tid + dd * 128;
        *(float4*)hm[d] =
            *(const float4*)(h + ((size_t)(b * 256 + d)) * 2048 + t0);
    }
    __syncthreads();

    auto mlp = [&](const float* w1, const float* b1, const float* w2,
                   const float* b2, float (*outbuf)[4]) {
        float bias = b1[tid];
        float a0 = bias, a1 = bias, a2 = bias, a3 = bias;
        for (int d = 0; d < 256; d++) {
            float w = w1[d * 128 + tid];
            float4 hv = *(const float4*)hm[d];
            a0 += hv.x * w; a1 += hv.y * w; a2 += hv.z * w; a3 += hv.w * w;
        }
        a0 = silu(a0); a1 = silu(a1); a2 = silu(a2); a3 = silu(a3);
        hid[tid][0] = a0; hid[tid][1] = a1; hid[tid][2] = a2; hid[tid][3] = a3;
        __syncthreads();
        float bias2 = b2[tid];
        float o0 = bias2, o1 = bias2, o2 = bias2, o3 = bias2;
        for (int j = 0; j < 128; j++) {
            float w = w2[j * 128 + tid];
            float4 hv = *(const float4*)hid[j];
            o0 += hv.x * w; o1 += hv.y * w; o2 += hv.z * w; o3 += hv.w * w;
        }
        outbuf[tid][0] = o0; outbuf[tid][1] = o1;
        outbuf[tid][2] = o2; outbuf[tid][3] = o3;
        __syncthreads();
    };

    const int head = tid >> 4;
    const int dim  = tid & 15;
    const int p    = dim >> 1;
    // 10000^(-p/8) = 2^(-p*0.125*log2(10000))
    const float inv = exp2f(-(float)p * 0.125f * 13.28771238f);

    // ---- q ----
    mlp(qw1, qb1, qw2, qb2, tmp);
    #pragma unroll
    for (int tt = 0; tt < 4; tt++) {
        float f = (float)(t0 + tt) * inv;
        float cs = cosf(f), sn = sinf(f);
        float a  = tmp[tid][tt];
        float pr = tmp[tid ^ 1][tt];
        float o  = (dim & 1) ? (a * cs + pr * sn) : (a * cs - pr * sn);
        q_ws[(((size_t)(b * 8 + head)) * 2048 + t0 + tt) * 16 + dim] = o;
    }
    __syncthreads();

    // ---- k ----
    mlp(kw1, kb1, kw2, kb2, tmp);
    #pragma unroll
    for (int tt = 0; tt < 4; tt++) {
        float f = (float)(t0 + tt) * inv;
        float cs = cosf(f), sn = sinf(f);
        float a  = tmp[tid][tt];
        float pr = tmp[tid ^ 1][tt];
        float o  = (dim & 1) ? (a * cs + pr * sn) : (a * cs - pr * sn);
        k_ws[(((size_t)(b * 8 + head)) * 2048 + t0 + tt) * 16 + dim] = o;
    }
    __syncthreads();

    // ---- v ----
    mlp(vw1, vb1, vw2, vb2, vout);
    #pragma unroll
    for (int tt = 0; tt < 4; tt++) {
        vext_ws[(((size_t)(b * 8 + head)) * 2048 + t0 + tt) * 20 + dim] =
            vout[tid][tt];
    }

    // ---- xm MLP: v(128) -> hid(128) -> v_x(8) ----
    {
        float bias = xmb1[tid];
        float a0 = bias, a1 = bias, a2 = bias, a3 = bias;
        for (int j = 0; j < 128; j++) {
            float w = xmw1[j * 128 + tid];
            float4 vv = *(const float4*)vout[j];
            a0 += vv.x * w; a1 += vv.y * w; a2 += vv.z * w; a3 += vv.w * w;
        }
        a0 = silu(a0); a1 = silu(a1); a2 = silu(a2); a3 = silu(a3);
        hid[tid][0] = a0; hid[tid][1] = a1; hid[tid][2] = a2; hid[tid][3] = a3;
        __syncthreads();
        if (tid < 32) {
            int hh = tid >> 2, tt = tid & 3;
            float s = xmb2[hh];
            for (int j = 0; j < 128; j++)
                s += hid[j][tt] * xmw2[j * 8 + hh];
            vx[hh][tt] = s;
        }
        __syncthreads();
    }

    // V' columns 16..19: [v_x, v_x*x_c]. 8 heads * 4 cols * 4 tokens = 128
    if (tid < 128) {
        int hh = tid >> 4;
        int c  = (tid >> 2) & 3;
        int tt = tid & 3;
        float val = vx[hh][tt];
        if (c)
            val *= x[((size_t)(b * 3 + (c - 1))) * 2048 + t0 + tt];
        vext_ws[(((size_t)(b * 8 + hh)) * 2048 + t0 + tt) * 20 + 16 + c] = val;
    }
}

// ---------------------------------------------------------------------------
// Kernel 2: flash attention with 20-wide extended values.
// Block: 256 threads = 4 waves. 64 queries per block (r = tid&63 owns a row,
// g = tid>>6 owns key sub-range and keeps a 20-wide O partial in registers).
// Grid: B*H * T/64 = 1024 blocks.
// ---------------------------------------------------------------------------
__global__ __launch_bounds__(256) void attn_kernel(
    const float* __restrict__ q_ws, const float* __restrict__ k_ws,
    const float* __restrict__ vext_ws, float* __restrict__ o_ws)
{
    const int blk = blockIdx.x;
    const int bh  = blk >> 5;
    const int qt  = blk & 31;
    const int tid = threadIdx.x;
    const int r   = tid & 63;
    const int g   = tid >> 6;

    __shared__ __align__(16) float Qs[64][16];
    __shared__ __align__(16) float Ks[64][16];
    __shared__ __align__(16) float Vs[64][20];
    __shared__ __align__(16) float Osum[64][20];
    __shared__ float mrow[64], lrow[64], arow[64];
    __shared__ float pmax[64][4], psum[64][4];

    const float* qbase = q_ws + ((size_t)bh * 2048 + qt * 64) * 16;
    ((float4*)Qs)[tid] = ((const float4*)qbase)[tid];
    if (tid < 64) { mrow[tid] = -1e9f; lrow[tid] = 0.f; }
    __syncthreads();

    float qreg[16];
    #pragma unroll
    for (int d = 0; d < 4; d++) {
        float4 qv = ((const float4*)Qs[r])[d];
        qreg[4 * d + 0] = qv.x; qreg[4 * d + 1] = qv.y;
        qreg[4 * d + 2] = qv.z; qreg[4 * d + 3] = qv.w;
    }

    float oreg[20];
    #pragma unroll
    for (int c = 0; c < 20; c++) oreg[c] = 0.f;

    const float4* kg = (const float4*)(k_ws + (size_t)bh * 2048 * 16);
    const float4* vg = (const float4*)(vext_ws + (size_t)bh * 2048 * 20);

    for (int kt = 0; kt < 32; kt++) {
        __syncthreads();
        ((float4*)Ks)[tid] = kg[kt * 256 + tid];
        ((float4*)Vs)[tid] = vg[kt * 320 + tid];
        if (tid < 64) ((float4*)Vs)[256 + tid] = vg[kt * 320 + 256 + tid];
        __syncthreads();

        float sreg[16];
        float locmax = -1e9f;
        #pragma unroll
        for (int jj = 0; jj < 16; jj++) {
            int j = (g << 4) | jj;
            const float4* kr = (const float4*)Ks[j];
            float4 k0 = kr[0], k1 = kr[1], k2 = kr[2], k3 = kr[3];
            float s = qreg[0]*k0.x + qreg[1]*k0.y + qreg[2]*k0.z + qreg[3]*k0.w
                    + qreg[4]*k1.x + qreg[5]*k1.y + qreg[6]*k1.z + qreg[7]*k1.w
                    + qreg[8]*k2.x + qreg[9]*k2.y + qreg[10]*k2.z + qreg[11]*k2.w
                    + qreg[12]*k3.x + qreg[13]*k3.y + qreg[14]*k3.z + qreg[15]*k3.w;
            s *= 0.25f;  // 1/sqrt(KQ)
            sreg[jj] = s;
            locmax = fmaxf(locmax, s);
        }
        pmax[r][g] = locmax;
        __syncthreads();
        if (tid < 64) {
            float mt = fmaxf(fmaxf(pmax[tid][0], pmax[tid][1]),
                             fmaxf(pmax[tid][2], pmax[tid][3]));
            float mold = mrow[tid];
            float mnew = fmaxf(mold, mt);
            arow[tid] = __expf(mold - mnew);
            mrow[tid] = mnew;
        }
        __syncthreads();
        float mnew  = mrow[r];
        float alpha = arow[r];
        #pragma unroll
        for (int c = 0; c < 20; c++) oreg[c] *= alpha;
        float ps = 0.f;
        #pragma unroll
        for (int jj = 0; jj < 16; jj++) {
            int j = (g << 4) | jj;
            float p = __expf(sreg[jj] - mnew);
            ps += p;
            const float4* vr = (const float4*)Vs[j];
            float4 v0 = vr[0], v1 = vr[1], v2 = vr[2], v3 = vr[3], v4 = vr[4];
            oreg[0]  += p * v0.x; oreg[1]  += p * v0.y;
            oreg[2]  += p * v0.z; oreg[3]  += p * v0.w;
            oreg[4]  += p * v1.x; oreg[5]  += p * v1.y;
            oreg[6]  += p * v1.z; oreg[7]  += p * v1.w;
            oreg[8]  += p * v2.x; oreg[9]  += p * v2.y;
            oreg[10] += p * v2.z; oreg[11] += p * v2.w;
            oreg[12] += p * v3.x; oreg[13] += p * v3.y;
            oreg[14] += p * v3.z; oreg[15] += p * v3.w;
            oreg[16] += p * v4.x; oreg[17] += p * v4.y;
            oreg[18] += p * v4.z; oreg[19] += p * v4.w;
        }
        psum[r][g] = ps;
        __syncthreads();
        if (tid < 64)
            lrow[tid] = lrow[tid] * arow[tid]
                      + psum[tid][0] + psum[tid][1] + psum[tid][2] + psum[tid][3];
    }
    __syncthreads();

    // reduce the 4 per-group O partials
    for (int gg = 0; gg < 4; gg++) {
        if (g == gg) {
            if (gg == 0) {
                #pragma unroll
                for (int c = 0; c < 20; c++) Osum[r][c] = oreg[c];
            } else {
                #pragma unroll
                for (int c = 0; c < 20; c++) Osum[r][c] += oreg[c];
            }
        }
        __syncthreads();
    }
    float linv = 1.f / lrow[r];
    float* ob = o_ws + ((size_t)bh * 2048 + qt * 64 + r) * 20 + g * 5;
    #pragma unroll
    for (int cc = 0; cc < 5; cc++) ob[cc] = Osum[r][g * 5 + cc] * linv;
}

// ---------------------------------------------------------------------------
// Kernel 3: epilogue. h_out = h + (O_heads @ ho_w + ho_b); x_out = x + GVP.
// 4 tokens per block (256 threads). Grid: 2048 blocks. OUTPUT IS FP32:
// d_out = [x_out (4*3*2048 = 24576 floats) | h_out (4*256*2048 floats)].
// ---------------------------------------------------------------------------
__global__ __launch_bounds__(256) void epi_kernel(
    const float* __restrict__ o_ws,
    const float* __restrict__ x, const float* __restrict__ hin,
    const float* __restrict__ how, const float* __restrict__ hob,
    const float* __restrict__ Wh, const float* __restrict__ Wu,
    float* __restrict__ out)
{
    const int blk = blockIdx.x;
    const int b  = blk >> 9;
    const int t0 = (blk & 511) << 2;
    const int tid = threadIdx.x;

    __shared__ __align__(16) float hv[128][4];
    __shared__ float gamma[8][4], wx[8][3][4];
    __shared__ float weff[8];

    for (int i = tid; i < 512; i += 256) {
        int j = i >> 2, tt = i & 3;
        hv[j][tt] =
            o_ws[(((size_t)b * 8 + (j >> 4)) * 2048 + t0 + tt) * 20 + (j & 15)];
    }
    if (tid < 128) {
        int tt = tid & 3;
        int idx = tid >> 2;
        int head = idx >> 2, c = idx & 3;
        float v = o_ws[(((size_t)b * 8 + head) * 2048 + t0 + tt) * 20 + 16 + c];
        if (c == 0) gamma[head][tt] = v; else wx[head][c - 1][tt] = v;
    } else if (tid < 136) {
        int v = tid - 128;
        float s = 0.f;
        for (int j = 0; j < 8; j++) s += Wh[v * 8 + j] * Wu[j];
        weff[v] = s;
    }
    __syncthreads();

    // h projection: thread owns output dim d = tid for 4 tokens
    float acc0 = 0.f, acc1 = 0.f, acc2 = 0.f, acc3 = 0.f;
    for (int j = 0; j < 128; j++) {
        float w = how[j * 256 + tid];
        float4 hvj = *(const float4*)hv[j];
        acc0 += hvj.x * w; acc1 += hvj.y * w; acc2 += hvj.z * w; acc3 += hvj.w * w;
    }
    float bias = hob[tid];
    size_t hbase = ((size_t)b * 256 + tid) * 2048 + t0;
    float4 hold = *(const float4*)(hin + hbase);
    float4 hres;
    hres.x = hold.x + acc0 + bias;
    hres.y = hold.y + acc1 + bias;
    hres.z = hold.z + acc2 + bias;
    hres.w = hold.w + acc3 + bias;
    *(float4*)(out + 24576 + hbase) = hres;

    // GVP / x_out: one thread per token
    if (tid < 4) {
        int tt = tid;
        int t = t0 + tt;
        float Vu[3], xv[3];
        #pragma unroll
        for (int c = 0; c < 3; c++) {
            xv[c] = x[((size_t)b * 3 + c) * 2048 + t];
            float s = 0.f;
            #pragma unroll
            for (int v = 0; v < 8; v++)
                s += (gamma[v][tt] * xv[c] - wx[v][c][tt]) * weff[v];
            Vu[c] = s;
        }
        float gate = sqrtf(Vu[0]*Vu[0] + Vu[1]*Vu[1] + Vu[2]*Vu[2]);
        float sg = 1.f / (1.f + __expf(-gate));
        #pragma unroll
        for (int c = 0; c < 3; c++)
            out[((size_t)b * 3 + c) * 2048 + t] = xv[c] + sg * Vu[c];
    }
}

// ---------------------------------------------------------------------------
extern "C" void kernel_launch(void* const* d_in, const int* in_sizes, int n_in,
                              void* d_out, int out_size, void* d_ws,
                              size_t ws_size, hipStream_t stream)
{
    const float* x    = (const float*)d_in[0];
    const float* h    = (const float*)d_in[1];
    const float* qw1  = (const float*)d_in[2];
    const float* qb1  = (const float*)d_in[3];
    const float* qw2  = (const float*)d_in[4];
    const float* qb2  = (const float*)d_in[5];
    const float* kw1  = (const float*)d_in[6];
    const float* kb1  = (const float*)d_in[7];
    const float* kw2  = (const float*)d_in[8];
    const float* kb2  = (const float*)d_in[9];
    const float* vw1  = (const float*)d_in[10];
    const float* vb1  = (const float*)d_in[11];
    const float* vw2  = (const float*)d_in[12];
    const float* vb2  = (const float*)d_in[13];
    const float* xmw1 = (const float*)d_in[14];
    const float* xmb1 = (const float*)d_in[15];
    const float* xmw2 = (const float*)d_in[16];
    const float* xmb2 = (const float*)d_in[17];
    const float* how  = (const float*)d_in[18];
    const float* hob  = (const float*)d_in[19];
    const float* Wh   = (const float*)d_in[20];
    const float* Wu   = (const float*)d_in[21];
    float* out = (float*)d_out;   // reference outputs are fp32

    float* ws      = (float*)d_ws;
    float* q_ws    = ws;                       // B*H*T*16 = 1,048,576 floats
    float* k_ws    = q_ws + 4 * 8 * 2048 * 16;
    float* vext_ws = k_ws + 4 * 8 * 2048 * 16; // B*H*T*20 = 1,310,720 floats
    float* o_ws    = vext_ws + 4 * 8 * 2048 * 20;

    qkv_kernel<<<2048, 128, 0, stream>>>(
        x, h, qw1, qb1, qw2, qb2, kw1, kb1, kw2, kb2,
        vw1, vb1, vw2, vb2, xmw1, xmb1, xmw2, xmb2,
        q_ws, k_ws, vext_ws);
    attn_kernel<<<1024, 256, 0, stream>>>(q_ws, k_ws, vext_ws, o_ws);
    epi_kernel<<<2048, 256, 0, stream>>>(o_ws, x, h, how, hob, Wh, Wu, out);
}

// Round 6
// 394.280 us; speedup vs baseline: 1.5863x; 1.5863x over previous
//
#include <hip/hip_runtime.h>
#include <hip/hip_bf16.h>
#include <math.h>

__device__ __forceinline__ float silu(float a) {
    return a / (1.f + __expf(-a));
}

// ---------------------------------------------------------------------------
// Kernel 1: per-token MLPs (q/k/v), RoPE(q,k), xm MLP -> v_x, build V' [T,20].
// 4 tokens per block (128 threads). Grid: B * T/4 = 2048 blocks.
// ---------------------------------------------------------------------------
__global__ __launch_bounds__(128) void qkv_kernel(
    const float* __restrict__ x, const float* __restrict__ h,
    const float* __restrict__ qw1, const float* __restrict__ qb1,
    const float* __restrict__ qw2, const float* __restrict__ qb2,
    const float* __restrict__ kw1, const float* __restrict__ kb1,
    const float* __restrict__ kw2, const float* __restrict__ kb2,
    const float* __restrict__ vw1, const float* __restrict__ vb1,
    const float* __restrict__ vw2, const float* __restrict__ vb2,
    const float* __restrict__ xmw1, const float* __restrict__ xmb1,
    const float* __restrict__ xmw2, const float* __restrict__ xmb2,
    float* __restrict__ q_ws, float* __restrict__ k_ws,
    float* __restrict__ vext_ws)
{
    const int blk = blockIdx.x;
    const int b  = blk >> 9;            // T/4 = 512 blocks per batch
    const int t0 = (blk & 511) << 2;
    const int tid = threadIdx.x;

    __shared__ __align__(16) float hm[256][4];
    __shared__ __align__(16) float hid[128][4];
    __shared__ __align__(16) float vout[128][4];
    __shared__ __align__(16) float tmp[128][4];
    __shared__ float vx[8][4];

    // load h_m: h is [B, D, T] fp32; 4 consecutive t -> one float4 per d
    #pragma unroll
    for (int dd = 0; dd < 2; dd++) {
        int d = tid + dd * 128;
        *(float4*)hm[d] =
            *(const float4*)(h + ((size_t)(b * 256 + d)) * 2048 + t0);
    }
    __syncthreads();

    auto mlp = [&](const float* w1, const float* b1, const float* w2,
                   const float* b2, float (*outbuf)[4]) {
        float bias = b1[tid];
        float a0 = bias, a1 = bias, a2 = bias, a3 = bias;
        for (int d = 0; d < 256; d++) {
            float w = w1[d * 128 + tid];
            float4 hv = *(const float4*)hm[d];
            a0 += hv.x * w; a1 += hv.y * w; a2 += hv.z * w; a3 += hv.w * w;
        }
        a0 = silu(a0); a1 = silu(a1); a2 = silu(a2); a3 = silu(a3);
        hid[tid][0] = a0; hid[tid][1] = a1; hid[tid][2] = a2; hid[tid][3] = a3;
        __syncthreads();
        float bias2 = b2[tid];
        float o0 = bias2, o1 = bias2, o2 = bias2, o3 = bias2;
        for (int j = 0; j < 128; j++) {
            float w = w2[j * 128 + tid];
            float4 hv = *(const float4*)hid[j];
            o0 += hv.x * w; o1 += hv.y * w; o2 += hv.z * w; o3 += hv.w * w;
        }
        outbuf[tid][0] = o0; outbuf[tid][1] = o1;
        outbuf[tid][2] = o2; outbuf[tid][3] = o3;
        __syncthreads();
    };

    const int head = tid >> 4;
    const int dim  = tid & 15;
    const int p    = dim >> 1;
    // 10000^(-p/8) = 2^(-p*0.125*log2(10000))
    const float inv = exp2f(-(float)p * 0.125f * 13.28771238f);

    // ---- q ----
    mlp(qw1, qb1, qw2, qb2, tmp);
    #pragma unroll
    for (int tt = 0; tt < 4; tt++) {
        float f = (float)(t0 + tt) * inv;
        float cs = cosf(f), sn = sinf(f);
        float a  = tmp[tid][tt];
        float pr = tmp[tid ^ 1][tt];
        float o  = (dim & 1) ? (a * cs + pr * sn) : (a * cs - pr * sn);
        q_ws[(((size_t)(b * 8 + head)) * 2048 + t0 + tt) * 16 + dim] = o;
    }
    __syncthreads();

    // ---- k ----
    mlp(kw1, kb1, kw2, kb2, tmp);
    #pragma unroll
    for (int tt = 0; tt < 4; tt++) {
        float f = (float)(t0 + tt) * inv;
        float cs = cosf(f), sn = sinf(f);
        float a  = tmp[tid][tt];
        float pr = tmp[tid ^ 1][tt];
        float o  = (dim & 1) ? (a * cs + pr * sn) : (a * cs - pr * sn);
        k_ws[(((size_t)(b * 8 + head)) * 2048 + t0 + tt) * 16 + dim] = o;
    }
    __syncthreads();

    // ---- v ----
    mlp(vw1, vb1, vw2, vb2, vout);
    #pragma unroll
    for (int tt = 0; tt < 4; tt++) {
        vext_ws[(((size_t)(b * 8 + head)) * 2048 + t0 + tt) * 20 + dim] =
            vout[tid][tt];
    }

    // ---- xm MLP: v(128) -> hid(128) -> v_x(8) ----
    {
        float bias = xmb1[tid];
        float a0 = bias, a1 = bias, a2 = bias, a3 = bias;
        for (int j = 0; j < 128; j++) {
            float w = xmw1[j * 128 + tid];
            float4 vv = *(const float4*)vout[j];
            a0 += vv.x * w; a1 += vv.y * w; a2 += vv.z * w; a3 += vv.w * w;
        }
        a0 = silu(a0); a1 = silu(a1); a2 = silu(a2); a3 = silu(a3);
        hid[tid][0] = a0; hid[tid][1] = a1; hid[tid][2] = a2; hid[tid][3] = a3;
        __syncthreads();
        if (tid < 32) {
            int hh = tid >> 2, tt = tid & 3;
            float s = xmb2[hh];
            for (int j = 0; j < 128; j++)
                s += hid[j][tt] * xmw2[j * 8 + hh];
            vx[hh][tt] = s;
        }
        __syncthreads();
    }

    // V' columns 16..19: [v_x, v_x*x_c]. 8 heads * 4 cols * 4 tokens = 128
    if (tid < 128) {
        int hh = tid >> 4;
        int c  = (tid >> 2) & 3;
        int tt = tid & 3;
        float val = vx[hh][tt];
        if (c)
            val *= x[((size_t)(b * 3 + (c - 1))) * 2048 + t0 + tt];
        vext_ws[(((size_t)(b * 8 + hh)) * 2048 + t0 + tt) * 20 + 16 + c] = val;
    }
}

// ---------------------------------------------------------------------------
// Kernel 2: flash attention, thread-per-query, 4-way key split.
// Block: 64 threads = 1 wave = 64 queries; each block covers 512 keys.
// Grid: 32 bh * 32 qtiles * 4 splits = 4096 blocks.
// Private online softmax (no cross-thread state); K/V LDS reads are
// wave-uniform broadcasts (conflict-free). Emits unnormalized partials.
// ---------------------------------------------------------------------------
__global__ __launch_bounds__(64, 4) void attn_kernel(
    const float* __restrict__ q_ws, const float* __restrict__ k_ws,
    const float* __restrict__ vext_ws,
    float* __restrict__ Opart, float* __restrict__ MLpart)
{
    const int blk  = blockIdx.x;
    const int bh   = blk >> 7;          // 128 blocks per bh
    const int rem  = blk & 127;
    const int qt   = rem >> 2;          // 0..31 query tile
    const int sp   = rem & 3;           // key split
    const int lane = threadIdx.x;       // 0..63
    const int qi   = qt * 64 + lane;

    __shared__ __align__(16) float Ks[64 * 16];
    __shared__ __align__(16) float Vs[64 * 20];

    float qreg[16];
    {
        const float4* qb =
            (const float4*)(q_ws + ((size_t)bh * 2048 + qi) * 16);
        #pragma unroll
        for (int d = 0; d < 4; d++) {
            float4 v = qb[d];
            qreg[4 * d + 0] = v.x; qreg[4 * d + 1] = v.y;
            qreg[4 * d + 2] = v.z; qreg[4 * d + 3] = v.w;
        }
    }

    float m = -1e9f, l = 0.f;
    float o[20];
    #pragma unroll
    for (int c = 0; c < 20; c++) o[c] = 0.f;

    const float4* kg =
        (const float4*)(k_ws + ((size_t)bh * 2048 + sp * 512) * 16);
    const float4* vg =
        (const float4*)(vext_ws + ((size_t)bh * 2048 + sp * 512) * 20);

    for (int kt = 0; kt < 8; kt++) {            // 8 tiles of 64 keys
        __syncthreads();
        #pragma unroll
        for (int i = 0; i < 4; i++)
            ((float4*)Ks)[i * 64 + lane] = kg[kt * 256 + i * 64 + lane];
        #pragma unroll
        for (int i = 0; i < 5; i++)
            ((float4*)Vs)[i * 64 + lane] = vg[kt * 320 + i * 64 + lane];
        __syncthreads();

        #pragma unroll
        for (int cc = 0; cc < 4; cc++) {        // chunks of 16 keys
            float sreg[16];
            float cmax = -1e9f;
            #pragma unroll
            for (int jj = 0; jj < 16; jj++) {
                const float* kr = Ks + (cc * 16 + jj) * 16;
                float4 k0 = ((const float4*)kr)[0];
                float4 k1 = ((const float4*)kr)[1];
                float4 k2 = ((const float4*)kr)[2];
                float4 k3 = ((const float4*)kr)[3];
                float s = qreg[0]*k0.x + qreg[1]*k0.y + qreg[2]*k0.z + qreg[3]*k0.w
                        + qreg[4]*k1.x + qreg[5]*k1.y + qreg[6]*k1.z + qreg[7]*k1.w
                        + qreg[8]*k2.x + qreg[9]*k2.y + qreg[10]*k2.z + qreg[11]*k2.w
                        + qreg[12]*k3.x + qreg[13]*k3.y + qreg[14]*k3.z + qreg[15]*k3.w;
                s *= 0.25f;                     // 1/sqrt(KQ)
                sreg[jj] = s;
                cmax = fmaxf(cmax, s);
            }
            float mnew  = fmaxf(m, cmax);
            float alpha = __expf(m - mnew);
            l *= alpha;
            #pragma unroll
            for (int c = 0; c < 20; c++) o[c] *= alpha;
            #pragma unroll
            for (int jj = 0; jj < 16; jj++) {
                float p = __expf(sreg[jj] - mnew);
                l += p;
                const float* vr = Vs + (cc * 16 + jj) * 20;
                float4 v0 = ((const float4*)vr)[0];
                float4 v1 = ((const float4*)vr)[1];
                float4 v2 = ((const float4*)vr)[2];
                float4 v3 = ((const float4*)vr)[3];
                float4 v4 = ((const float4*)vr)[4];
                o[0]  += p * v0.x; o[1]  += p * v0.y;
                o[2]  += p * v0.z; o[3]  += p * v0.w;
                o[4]  += p * v1.x; o[5]  += p * v1.y;
                o[6]  += p * v1.z; o[7]  += p * v1.w;
                o[8]  += p * v2.x; o[9]  += p * v2.y;
                o[10] += p * v2.z; o[11] += p * v2.w;
                o[12] += p * v3.x; o[13] += p * v3.y;
                o[14] += p * v3.z; o[15] += p * v3.w;
                o[16] += p * v4.x; o[17] += p * v4.y;
                o[18] += p * v4.z; o[19] += p * v4.w;
            }
            m = mnew;
        }
    }

    // unnormalized partial + (m, l)
    float* ob = Opart + (((size_t)bh * 4 + sp) * 2048 + qi) * 20;
    #pragma unroll
    for (int c = 0; c < 20; c++) ob[c] = o[c];
    float* mb = MLpart + (((size_t)bh * 4 + sp) * 2048 + qi) * 2;
    mb[0] = m; mb[1] = l;
}

// ---------------------------------------------------------------------------
// Kernel 3: epilogue. Combines the 4 key-split partials (log-sum-exp merge),
// then h_out = h + (O_heads @ ho_w + ho_b); x_out = x + GVP.
// 4 tokens per block (256 threads). Grid: 2048 blocks. Output fp32.
// ---------------------------------------------------------------------------
__global__ __launch_bounds__(256) void epi_kernel(
    const float* __restrict__ Opart, const float* __restrict__ MLpart,
    const float* __restrict__ x, const float* __restrict__ hin,
    const float* __restrict__ how, const float* __restrict__ hob,
    const float* __restrict__ Wh, const float* __restrict__ Wu,
    float* __restrict__ out)
{
    const int blk = blockIdx.x;
    const int b  = blk >> 9;
    const int t0 = (blk & 511) << 2;
    const int tid = threadIdx.x;

    __shared__ __align__(16) float hv[128][4];
    __shared__ float gamma[8][4], wx[8][3][4];
    __shared__ float weff[8];

    // combine splits: thread (head, tt), 32 threads
    if (tid < 32) {
        int head = tid >> 2, tt = tid & 3;
        int bh = b * 8 + head;
        int t  = t0 + tt;
        float ms[4], ls[4], M = -1e30f;
        #pragma unroll
        for (int sp = 0; sp < 4; sp++) {
            const float* mb = MLpart + (((size_t)bh * 4 + sp) * 2048 + t) * 2;
            ms[sp] = mb[0]; ls[sp] = mb[1];
            M = fmaxf(M, ms[sp]);
        }
        float L = 0.f, w[4];
        #pragma unroll
        for (int sp = 0; sp < 4; sp++) {
            w[sp] = __expf(ms[sp] - M);
            L += ls[sp] * w[sp];
        }
        float Linv = 1.f / L;
        float Ov[20];
        #pragma unroll
        for (int c = 0; c < 20; c++) Ov[c] = 0.f;
        #pragma unroll
        for (int sp = 0; sp < 4; sp++) {
            const float* ob = Opart + (((size_t)bh * 4 + sp) * 2048 + t) * 20;
            #pragma unroll
            for (int c = 0; c < 20; c++) Ov[c] += ob[c] * w[sp];
        }
        #pragma unroll
        for (int d = 0; d < 16; d++) hv[head * 16 + d][tt] = Ov[d] * Linv;
        gamma[head][tt] = Ov[16] * Linv;
        wx[head][0][tt] = Ov[17] * Linv;
        wx[head][1][tt] = Ov[18] * Linv;
        wx[head][2][tt] = Ov[19] * Linv;
    } else if (tid < 40) {
        int v = tid - 32;
        float s = 0.f;
        for (int j = 0; j < 8; j++) s += Wh[v * 8 + j] * Wu[j];
        weff[v] = s;
    }
    __syncthreads();

    // h projection: thread owns output dim d = tid for 4 tokens
    float acc0 = 0.f, acc1 = 0.f, acc2 = 0.f, acc3 = 0.f;
    for (int j = 0; j < 128; j++) {
        float w = how[j * 256 + tid];
        float4 hvj = *(const float4*)hv[j];
        acc0 += hvj.x * w; acc1 += hvj.y * w; acc2 += hvj.z * w; acc3 += hvj.w * w;
    }
    float bias = hob[tid];
    size_t hbase = ((size_t)b * 256 + tid) * 2048 + t0;
    float4 hold = *(const float4*)(hin + hbase);
    float4 hres;
    hres.x = hold.x + acc0 + bias;
    hres.y = hold.y + acc1 + bias;
    hres.z = hold.z + acc2 + bias;
    hres.w = hold.w + acc3 + bias;
    *(float4*)(out + 24576 + hbase) = hres;

    // GVP / x_out: one thread per token
    if (tid < 4) {
        int tt = tid;
        int t = t0 + tt;
        float Vu[3], xv[3];
        #pragma unroll
        for (int c = 0; c < 3; c++) {
            xv[c] = x[((size_t)b * 3 + c) * 2048 + t];
            float s = 0.f;
            #pragma unroll
            for (int v = 0; v < 8; v++)
                s += (gamma[v][tt] * xv[c] - wx[v][c][tt]) * weff[v];
            Vu[c] = s;
        }
        float gate = sqrtf(Vu[0]*Vu[0] + Vu[1]*Vu[1] + Vu[2]*Vu[2]);
        float sg = 1.f / (1.f + __expf(-gate));
        #pragma unroll
        for (int c = 0; c < 3; c++)
            out[((size_t)b * 3 + c) * 2048 + t] = xv[c] + sg * Vu[c];
    }
}

// ---------------------------------------------------------------------------
extern "C" void kernel_launch(void* const* d_in, const int* in_sizes, int n_in,
                              void* d_out, int out_size, void* d_ws,
                              size_t ws_size, hipStream_t stream)
{
    const float* x    = (const float*)d_in[0];
    const float* h    = (const float*)d_in[1];
    const float* qw1  = (const float*)d_in[2];
    const float* qb1  = (const float*)d_in[3];
    const float* qw2  = (const float*)d_in[4];
    const float* qb2  = (const float*)d_in[5];
    const float* kw1  = (const float*)d_in[6];
    const float* kb1  = (const float*)d_in[7];
    const float* kw2  = (const float*)d_in[8];
    const float* kb2  = (const float*)d_in[9];
    const float* vw1  = (const float*)d_in[10];
    const float* vb1  = (const float*)d_in[11];
    const float* vw2  = (const float*)d_in[12];
    const float* vb2  = (const float*)d_in[13];
    const float* xmw1 = (const float*)d_in[14];
    const float* xmb1 = (const float*)d_in[15];
    const float* xmw2 = (const float*)d_in[16];
    const float* xmb2 = (const float*)d_in[17];
    const float* how  = (const float*)d_in[18];
    const float* hob  = (const float*)d_in[19];
    const float* Wh   = (const float*)d_in[20];
    const float* Wu   = (const float*)d_in[21];
    float* out = (float*)d_out;   // reference outputs are fp32

    float* ws      = (float*)d_ws;
    float* q_ws    = ws;                         // 1,048,576 floats
    float* k_ws    = q_ws + 4 * 8 * 2048 * 16;   // 1,048,576
    float* vext_ws = k_ws + 4 * 8 * 2048 * 16;   // 1,310,720
    float* Opart   = vext_ws + 4 * 8 * 2048 * 20; // 32*4*2048*20 = 5,242,880
    float* MLpart  = Opart + 32 * 4 * 2048 * 20;  // 32*4*2048*2  =   524,288
    // total ws: 9,175,040 floats = 36.7 MB

    qkv_kernel<<<2048, 128, 0, stream>>>(
        x, h, qw1, qb1, qw2, qb2, kw1, kb1, kw2, kb2,
        vw1, vb1, vw2, vb2, xmw1, xmb1, xmw2, xmb2,
        q_ws, k_ws, vext_ws);
    attn_kernel<<<4096, 64, 0, stream>>>(q_ws, k_ws, vext_ws, Opart, MLpart);
    epi_kernel<<<2048, 256, 0, stream>>>(Opart, MLpart, x, h, how, hob, Wh, Wu, out);
}

// Round 7
// 290.048 us; speedup vs baseline: 2.1563x; 1.3594x over previous
//
#include <hip/hip_runtime.h>
#include <hip/hip_bf16.h>
#include <math.h>

typedef __attribute__((ext_vector_type(8))) short s16x8;   // 8 bf16
typedef __attribute__((ext_vector_type(4))) float f32x4;

__device__ __forceinline__ float silu(float a) {
    return a / (1.f + __expf(-a));
}
__device__ __forceinline__ unsigned short f2b(float f) {
    __hip_bfloat16 h = __float2bfloat16(f);
    return *reinterpret_cast<unsigned short*>(&h);
}

// ---------------------------------------------------------------------------
// Kernel 1: per-token MLPs (q/k/v), RoPE(q,k), xm MLP -> v_x.
// Outputs (bf16): q_bf [bh][t][16] (pre-scaled by 0.25), k_bf [bh][t][16],
// vT_bf [bh][32][t] (V' transposed, cols 20..31 zeroed).
// 4 tokens per block (128 threads). Grid: B * T/4 = 2048 blocks.
// ---------------------------------------------------------------------------
__global__ __launch_bounds__(128) void qkv_kernel(
    const float* __restrict__ x, const float* __restrict__ h,
    const float* __restrict__ qw1, const float* __restrict__ qb1,
    const float* __restrict__ qw2, const float* __restrict__ qb2,
    const float* __restrict__ kw1, const float* __restrict__ kb1,
    const float* __restrict__ kw2, const float* __restrict__ kb2,
    const float* __restrict__ vw1, const float* __restrict__ vb1,
    const float* __restrict__ vw2, const float* __restrict__ vb2,
    const float* __restrict__ xmw1, const float* __restrict__ xmb1,
    const float* __restrict__ xmw2, const float* __restrict__ xmb2,
    unsigned short* __restrict__ q_bf, unsigned short* __restrict__ k_bf,
    unsigned short* __restrict__ vT_bf)
{
    const int blk = blockIdx.x;
    const int b  = blk >> 9;            // T/4 = 512 blocks per batch
    const int t0 = (blk & 511) << 2;
    const int tid = threadIdx.x;

    __shared__ __align__(16) float hm[256][4];
    __shared__ __align__(16) float hid[128][4];
    __shared__ __align__(16) float vout[128][4];
    __shared__ __align__(16) float tmp[128][4];
    __shared__ float vx[8][4];

    #pragma unroll
    for (int dd = 0; dd < 2; dd++) {
        int d = tid + dd * 128;
        *(float4*)hm[d] =
            *(const float4*)(h + ((size_t)(b * 256 + d)) * 2048 + t0);
    }
    __syncthreads();

    auto mlp = [&](const float* w1, const float* b1, const float* w2,
                   const float* b2, float (*outbuf)[4]) {
        float bias = b1[tid];
        float a0 = bias, a1 = bias, a2 = bias, a3 = bias;
        for (int d = 0; d < 256; d++) {
            float w = w1[d * 128 + tid];
            float4 hv = *(const float4*)hm[d];
            a0 += hv.x * w; a1 += hv.y * w; a2 += hv.z * w; a3 += hv.w * w;
        }
        a0 = silu(a0); a1 = silu(a1); a2 = silu(a2); a3 = silu(a3);
        hid[tid][0] = a0; hid[tid][1] = a1; hid[tid][2] = a2; hid[tid][3] = a3;
        __syncthreads();
        float bias2 = b2[tid];
        float o0 = bias2, o1 = bias2, o2 = bias2, o3 = bias2;
        for (int j = 0; j < 128; j++) {
            float w = w2[j * 128 + tid];
            float4 hv = *(const float4*)hid[j];
            o0 += hv.x * w; o1 += hv.y * w; o2 += hv.z * w; o3 += hv.w * w;
        }
        outbuf[tid][0] = o0; outbuf[tid][1] = o1;
        outbuf[tid][2] = o2; outbuf[tid][3] = o3;
        __syncthreads();
    };

    const int head = tid >> 4;
    const int dim  = tid & 15;
    const int p    = dim >> 1;
    const float inv = exp2f(-(float)p * 0.125f * 13.28771238f);

    // ---- q (scaled by 0.25 = 1/sqrt(KQ), folded into bf16) ----
    mlp(qw1, qb1, qw2, qb2, tmp);
    #pragma unroll
    for (int tt = 0; tt < 4; tt++) {
        float f = (float)(t0 + tt) * inv;
        float cs = cosf(f), sn = sinf(f);
        float a  = tmp[tid][tt];
        float pr = tmp[tid ^ 1][tt];
        float o  = (dim & 1) ? (a * cs + pr * sn) : (a * cs - pr * sn);
        q_bf[(((size_t)(b * 8 + head)) * 2048 + t0 + tt) * 16 + dim] =
            f2b(o * 0.25f);
    }
    __syncthreads();

    // ---- k ----
    mlp(kw1, kb1, kw2, kb2, tmp);
    #pragma unroll
    for (int tt = 0; tt < 4; tt++) {
        float f = (float)(t0 + tt) * inv;
        float cs = cosf(f), sn = sinf(f);
        float a  = tmp[tid][tt];
        float pr = tmp[tid ^ 1][tt];
        float o  = (dim & 1) ? (a * cs + pr * sn) : (a * cs - pr * sn);
        k_bf[(((size_t)(b * 8 + head)) * 2048 + t0 + tt) * 16 + dim] = f2b(o);
    }
    __syncthreads();

    // ---- v ----  (transposed: vT_bf[bh][col][t])
    mlp(vw1, vb1, vw2, vb2, vout);
    #pragma unroll
    for (int tt = 0; tt < 4; tt++) {
        vT_bf[(((size_t)(b * 8 + head)) * 32 + dim) * 2048 + t0 + tt] =
            f2b(vout[tid][tt]);
    }

    // ---- xm MLP: v(128) -> hid(128) -> v_x(8) ----
    {
        float bias = xmb1[tid];
        float a0 = bias, a1 = bias, a2 = bias, a3 = bias;
        for (int j = 0; j < 128; j++) {
            float w = xmw1[j * 128 + tid];
            float4 vv = *(const float4*)vout[j];
            a0 += vv.x * w; a1 += vv.y * w; a2 += vv.z * w; a3 += vv.w * w;
        }
        a0 = silu(a0); a1 = silu(a1); a2 = silu(a2); a3 = silu(a3);
        hid[tid][0] = a0; hid[tid][1] = a1; hid[tid][2] = a2; hid[tid][3] = a3;
        __syncthreads();
        if (tid < 32) {
            int hh = tid >> 2, tt = tid & 3;
            float s = xmb2[hh];
            for (int j = 0; j < 128; j++)
                s += hid[j][tt] * xmw2[j * 8 + hh];
            vx[hh][tt] = s;
        }
        __syncthreads();
    }

    // V' cols 16..19: [v_x, v_x*x_c]
    if (tid < 128) {
        int hh = tid >> 4;
        int c  = (tid >> 2) & 3;
        int tt = tid & 3;
        float val = vx[hh][tt];
        if (c)
            val *= x[((size_t)(b * 3 + (c - 1))) * 2048 + t0 + tt];
        vT_bf[(((size_t)(b * 8 + hh)) * 32 + 16 + c) * 2048 + t0 + tt] =
            f2b(val);
    }
    // zero-pad cols 20..31 (read by the PV MFMA B-fragments)
    for (int i = tid; i < 384; i += 128) {     // 8 heads * 12 cols * 4 t
        int hh  = i / 48;
        int rem = i % 48;
        int c   = 20 + (rem >> 2);
        int tt  = rem & 3;
        vT_bf[(((size_t)(b * 8 + hh)) * 32 + c) * 2048 + t0 + tt] = 0;
    }
}

// ---------------------------------------------------------------------------
// Kernel 2: MFMA attention, no online softmax (scores bounded; fp32 exp safe).
// One wave per 16-query strip. Grid: 32 bh * 128 strips = 4096 blocks, 64 thr.
// Per 64-key tile: 4 QK MFMAs (K=16 zero-padded to 32), exp on C-frags,
// E->A-layout via LDS (bf16, 72-ushort padded rows), 4 PV MFMAs (K=32).
// ---------------------------------------------------------------------------
__global__ __launch_bounds__(64) void attn_mfma(
    const unsigned short* __restrict__ q_bf,
    const unsigned short* __restrict__ k_bf,
    const unsigned short* __restrict__ vT_bf,
    float* __restrict__ o_ws)
{
    const int blk  = blockIdx.x;
    const int bh   = blk >> 7;
    const int qs   = (blk & 127) << 4;
    const int lane = threadIdx.x;
    const int m_   = lane & 15;
    const int quad = lane >> 4;

    __shared__ __align__(16) unsigned short Elds[16 * 72];
    __shared__ float Llds[16 * 16];
    __shared__ float Linv[16];

    s16x8 qfrag = {0, 0, 0, 0, 0, 0, 0, 0};
    if (quad < 2)
        qfrag = *(const s16x8*)(q_bf +
                 ((size_t)(bh * 2048 + qs + m_) * 16 + quad * 8));

    f32x4 O0 = {0.f, 0.f, 0.f, 0.f};
    f32x4 O1 = {0.f, 0.f, 0.f, 0.f};
    f32x4 lsum = {0.f, 0.f, 0.f, 0.f};
    const f32x4 zero = {0.f, 0.f, 0.f, 0.f};

    const unsigned short* kb = k_bf  + (size_t)bh * 2048 * 16;
    const unsigned short* vb = vT_bf + (size_t)bh * 32 * 2048;

    for (int kt = 0; kt < 32; kt++) {
        const int k0 = kt * 64;

        // QK^T: E[n] covers keys k0+16n .. +15  (C: row=query, col=key)
        f32x4 E[4];
        #pragma unroll
        for (int n = 0; n < 4; n++) {
            s16x8 kf = {0, 0, 0, 0, 0, 0, 0, 0};
            if (quad < 2)
                kf = *(const s16x8*)(kb +
                      ((size_t)(k0 + n * 16 + m_) * 16 + quad * 8));
            E[n] = __builtin_amdgcn_mfma_f32_16x16x32_bf16(qfrag, kf, zero,
                                                           0, 0, 0);
        }

        // exp, row-sum partials, write E (bf16) to LDS in [query][key] order
        #pragma unroll
        for (int n = 0; n < 4; n++) {
            #pragma unroll
            for (int i = 0; i < 4; i++) {
                float e = __expf(E[n][i]);
                lsum[i] += e;
                Elds[(quad * 4 + i) * 72 + n * 16 + m_] = f2b(e);
            }
        }
        __syncthreads();   // single-wave: just drains LDS writes

        // PV: A = E chunk [16q x 32k], B = V' [32k x 16n] (two col-halves)
        #pragma unroll
        for (int c = 0; c < 2; c++) {
            s16x8 af = *(const s16x8*)(Elds + m_ * 72 + c * 32 + quad * 8);
            s16x8 b0 = *(const s16x8*)(vb + (size_t)m_ * 2048
                                          + k0 + c * 32 + quad * 8);
            s16x8 b1 = *(const s16x8*)(vb + (size_t)(16 + m_) * 2048
                                          + k0 + c * 32 + quad * 8);
            O0 = __builtin_amdgcn_mfma_f32_16x16x32_bf16(af, b0, O0, 0, 0, 0);
            O1 = __builtin_amdgcn_mfma_f32_16x16x32_bf16(af, b1, O1, 0, 0, 0);
        }
        __syncthreads();   // WAR before next tile's E writes
    }

    // row sums: lane holds partials for rows quad*4+i at col-residue m_
    #pragma unroll
    for (int i = 0; i < 4; i++)
        Llds[(quad * 4 + i) * 16 + m_] = lsum[i];
    __syncthreads();
    if (lane < 16) {
        float s = 0.f;
        #pragma unroll
        for (int c2 = 0; c2 < 16; c2++) s += Llds[lane * 16 + c2];
        Linv[lane] = 1.f / s;
    }
    __syncthreads();

    // normalize + store O (o_ws [bh][t][20], fp32)
    #pragma unroll
    for (int i = 0; i < 4; i++) {
        int row = quad * 4 + i;
        float li = Linv[row];
        float* ob = o_ws + ((size_t)bh * 2048 + qs + row) * 20;
        ob[m_] = O0[i] * li;
        if (m_ < 4) ob[16 + m_] = O1[i] * li;
    }
}

// ---------------------------------------------------------------------------
// Kernel 3: epilogue (round-5-verified). h_out = h + (O @ ho_w + ho_b);
// x_out = x + GVP. 4 tokens per block (256 threads). Grid: 2048. fp32 out.
// ---------------------------------------------------------------------------
__global__ __launch_bounds__(256) void epi_kernel(
    const float* __restrict__ o_ws,
    const float* __restrict__ x, const float* __restrict__ hin,
    const float* __restrict__ how, const float* __restrict__ hob,
    const float* __restrict__ Wh, const float* __restrict__ Wu,
    float* __restrict__ out)
{
    const int blk = blockIdx.x;
    const int b  = blk >> 9;
    const int t0 = (blk & 511) << 2;
    const int tid = threadIdx.x;

    __shared__ __align__(16) float hv[128][4];
    __shared__ float gamma[8][4], wx[8][3][4];
    __shared__ float weff[8];

    for (int i = tid; i < 512; i += 256) {
        int j = i >> 2, tt = i & 3;
        hv[j][tt] =
            o_ws[(((size_t)b * 8 + (j >> 4)) * 2048 + t0 + tt) * 20 + (j & 15)];
    }
    if (tid < 128) {
        int tt = tid & 3;
        int idx = tid >> 2;
        int head = idx >> 2, c = idx & 3;
        float v = o_ws[(((size_t)b * 8 + head) * 2048 + t0 + tt) * 20 + 16 + c];
        if (c == 0) gamma[head][tt] = v; else wx[head][c - 1][tt] = v;
    } else if (tid < 136) {
        int v = tid - 128;
        float s = 0.f;
        for (int j = 0; j < 8; j++) s += Wh[v * 8 + j] * Wu[j];
        weff[v] = s;
    }
    __syncthreads();

    float acc0 = 0.f, acc1 = 0.f, acc2 = 0.f, acc3 = 0.f;
    for (int j = 0; j < 128; j++) {
        float w = how[j * 256 + tid];
        float4 hvj = *(const float4*)hv[j];
        acc0 += hvj.x * w; acc1 += hvj.y * w; acc2 += hvj.z * w; acc3 += hvj.w * w;
    }
    float bias = hob[tid];
    size_t hbase = ((size_t)b * 256 + tid) * 2048 + t0;
    float4 hold = *(const float4*)(hin + hbase);
    float4 hres;
    hres.x = hold.x + acc0 + bias;
    hres.y = hold.y + acc1 + bias;
    hres.z = hold.z + acc2 + bias;
    hres.w = hold.w + acc3 + bias;
    *(float4*)(out + 24576 + hbase) = hres;

    if (tid < 4) {
        int tt = tid;
        int t = t0 + tt;
        float Vu[3], xv[3];
        #pragma unroll
        for (int c = 0; c < 3; c++) {
            xv[c] = x[((size_t)b * 3 + c) * 2048 + t];
            float s = 0.f;
            #pragma unroll
            for (int v = 0; v < 8; v++)
                s += (gamma[v][tt] * xv[c] - wx[v][c][tt]) * weff[v];
            Vu[c] = s;
        }
        float gate = sqrtf(Vu[0]*Vu[0] + Vu[1]*Vu[1] + Vu[2]*Vu[2]);
        float sg = 1.f / (1.f + __expf(-gate));
        #pragma unroll
        for (int c = 0; c < 3; c++)
            out[((size_t)b * 3 + c) * 2048 + t] = xv[c] + sg * Vu[c];
    }
}

// ---------------------------------------------------------------------------
extern "C" void kernel_launch(void* const* d_in, const int* in_sizes, int n_in,
                              void* d_out, int out_size, void* d_ws,
                              size_t ws_size, hipStream_t stream)
{
    const float* x    = (const float*)d_in[0];
    const float* h    = (const float*)d_in[1];
    const float* qw1  = (const float*)d_in[2];
    const float* qb1  = (const float*)d_in[3];
    const float* qw2  = (const float*)d_in[4];
    const float* qb2  = (const float*)d_in[5];
    const float* kw1  = (const float*)d_in[6];
    const float* kb1  = (const float*)d_in[7];
    const float* kw2  = (const float*)d_in[8];
    const float* kb2  = (const float*)d_in[9];
    const float* vw1  = (const float*)d_in[10];
    const float* vb1  = (const float*)d_in[11];
    const float* vw2  = (const float*)d_in[12];
    const float* vb2  = (const float*)d_in[13];
    const float* xmw1 = (const float*)d_in[14];
    const float* xmb1 = (const float*)d_in[15];
    const float* xmw2 = (const float*)d_in[16];
    const float* xmb2 = (const float*)d_in[17];
    const float* how  = (const float*)d_in[18];
    const float* hob  = (const float*)d_in[19];
    const float* Wh   = (const float*)d_in[20];
    const float* Wu   = (const float*)d_in[21];
    float* out = (float*)d_out;

    unsigned short* q_bf  = (unsigned short*)d_ws;          // 32*2048*16
    unsigned short* k_bf  = q_bf + (size_t)32 * 2048 * 16;  // 32*2048*16
    unsigned short* vT_bf = k_bf + (size_t)32 * 2048 * 16;  // 32*32*2048
    float* o_ws = (float*)(vT_bf + (size_t)32 * 32 * 2048); // 32*2048*20 fp32
    // bytes: 2M + 2M + 4M + 5.24M ≈ 13.3 MB

    qkv_kernel<<<2048, 128, 0, stream>>>(
        x, h, qw1, qb1, qw2, qb2, kw1, kb1, kw2, kb2,
        vw1, vb1, vw2, vb2, xmw1, xmb1, xmw2, xmb2,
        q_bf, k_bf, vT_bf);
    attn_mfma<<<4096, 64, 0, stream>>>(q_bf, k_bf, vT_bf, o_ws);
    epi_kernel<<<2048, 256, 0, stream>>>(o_ws, x, h, how, hob, Wh, Wu, out);
}

// Round 8
// 283.107 us; speedup vs baseline: 2.2092x; 1.0245x over previous
//
#include <hip/hip_runtime.h>
#include <hip/hip_bf16.h>
#include <math.h>

typedef __attribute__((ext_vector_type(8))) short s16x8;   // 8 bf16
typedef __attribute__((ext_vector_type(4))) float f32x4;

__device__ __forceinline__ float silu(float a) {
    return a / (1.f + __expf(-a));
}
__device__ __forceinline__ unsigned short f2b(float f) {
    __hip_bfloat16 h = __float2bfloat16(f);
    return *reinterpret_cast<unsigned short*>(&h);
}

// ---------------------------------------------------------------------------
// Kernel 1: per-token MLPs (q/k/v), RoPE(q,k), xm MLP -> v_x.
// 16 tokens per block, 256 threads (thread = outdim j x token-half th).
// Grid: B*T/16 = 512 blocks. fp32 math; outputs bf16 (q pre-scaled 0.25).
// ---------------------------------------------------------------------------
__global__ __launch_bounds__(256) void qkv_kernel(
    const float* __restrict__ x, const float* __restrict__ h,
    const float* __restrict__ qw1, const float* __restrict__ qb1,
    const float* __restrict__ qw2, const float* __restrict__ qb2,
    const float* __restrict__ kw1, const float* __restrict__ kb1,
    const float* __restrict__ kw2, const float* __restrict__ kb2,
    const float* __restrict__ vw1, const float* __restrict__ vb1,
    const float* __restrict__ vw2, const float* __restrict__ vb2,
    const float* __restrict__ xmw1, const float* __restrict__ xmb1,
    const float* __restrict__ xmw2, const float* __restrict__ xmb2,
    unsigned short* __restrict__ q_bf, unsigned short* __restrict__ k_bf,
    unsigned short* __restrict__ vT_bf)
{
    const int blk = blockIdx.x;
    const int b  = blk >> 7;            // 128 blocks per batch
    const int t0 = (blk & 127) << 4;
    const int tid = threadIdx.x;
    const int j   = tid & 127;
    const int th  = tid >> 7;           // 0/1
    const int tb  = th * 8;

    __shared__ __align__(16) float hm[256][20];
    __shared__ __align__(16) float hid[128][20];
    __shared__ __align__(16) float vout[128][20];
    __shared__ __align__(16) float tmp[128][20];
    __shared__ float vx[8][16];

    // stage h[b][d][t0..t0+15]: 4096 floats, 4 float4 per thread
    #pragma unroll
    for (int i = 0; i < 4; i++) {
        int idx = tid + i * 256;        // 0..1023
        int d   = idx >> 2;
        int tg  = (idx & 3) << 2;
        *(float4*)&hm[d][tg] =
            *(const float4*)(h + ((size_t)(b * 256 + d)) * 2048 + t0 + tg);
    }
    __syncthreads();

    auto mlp = [&](const float* w1, const float* b1, const float* w2,
                   const float* b2, float (*outbuf)[20]) {
        float acc[8];
        float bias = b1[j];
        #pragma unroll
        for (int i = 0; i < 8; i++) acc[i] = bias;
        for (int d = 0; d < 256; d++) {
            float w = w1[d * 128 + j];
            float4 h0 = *(const float4*)&hm[d][tb];
            float4 h1 = *(const float4*)&hm[d][tb + 4];
            acc[0] += h0.x * w; acc[1] += h0.y * w;
            acc[2] += h0.z * w; acc[3] += h0.w * w;
            acc[4] += h1.x * w; acc[5] += h1.y * w;
            acc[6] += h1.z * w; acc[7] += h1.w * w;
        }
        #pragma unroll
        for (int i = 0; i < 8; i++) hid[j][tb + i] = silu(acc[i]);
        __syncthreads();
        float bias2 = b2[j];
        #pragma unroll
        for (int i = 0; i < 8; i++) acc[i] = bias2;
        for (int d = 0; d < 128; d++) {
            float w = w2[d * 128 + j];
            float4 h0 = *(const float4*)&hid[d][tb];
            float4 h1 = *(const float4*)&hid[d][tb + 4];
            acc[0] += h0.x * w; acc[1] += h0.y * w;
            acc[2] += h0.z * w; acc[3] += h0.w * w;
            acc[4] += h1.x * w; acc[5] += h1.y * w;
            acc[6] += h1.z * w; acc[7] += h1.w * w;
        }
        #pragma unroll
        for (int i = 0; i < 8; i++) outbuf[j][tb + i] = acc[i];
        __syncthreads();
    };

    const int head = j >> 4;
    const int dim  = j & 15;
    const int p    = dim >> 1;
    const float inv = exp2f(-(float)p * 0.125f * 13.28771238f);

    // ---- q (x0.25 folded) ----
    mlp(qw1, qb1, qw2, qb2, tmp);
    #pragma unroll
    for (int i = 0; i < 8; i++) {
        int t = t0 + tb + i;
        float f = (float)t * inv;
        float cs = cosf(f), sn = sinf(f);
        float a  = tmp[j][tb + i];
        float pr = tmp[j ^ 1][tb + i];
        float o  = (dim & 1) ? (a * cs + pr * sn) : (a * cs - pr * sn);
        q_bf[(((size_t)(b * 8 + head)) * 2048 + t) * 16 + dim] = f2b(o * 0.25f);
    }
    __syncthreads();

    // ---- k ----
    mlp(kw1, kb1, kw2, kb2, tmp);
    #pragma unroll
    for (int i = 0; i < 8; i++) {
        int t = t0 + tb + i;
        float f = (float)t * inv;
        float cs = cosf(f), sn = sinf(f);
        float a  = tmp[j][tb + i];
        float pr = tmp[j ^ 1][tb + i];
        float o  = (dim & 1) ? (a * cs + pr * sn) : (a * cs - pr * sn);
        k_bf[(((size_t)(b * 8 + head)) * 2048 + t) * 16 + dim] = f2b(o);
    }
    __syncthreads();

    // ---- v ----  (vT_bf[bh][col][t], 16B vector store per thread)
    mlp(vw1, vb1, vw2, vb2, vout);
    {
        s16x8 pk;
        #pragma unroll
        for (int i = 0; i < 8; i++) pk[i] = (short)f2b(vout[j][tb + i]);
        *(s16x8*)(vT_bf + (((size_t)(b * 8 + head)) * 32 + dim) * 2048
                        + t0 + tb) = pk;
    }

    // ---- xm MLP: v(128) -> hid(128) -> v_x(8) ----
    {
        float acc[8];
        float bias = xmb1[j];
        #pragma unroll
        for (int i = 0; i < 8; i++) acc[i] = bias;
        for (int d = 0; d < 128; d++) {
            float w = xmw1[d * 128 + j];
            float4 h0 = *(const float4*)&vout[d][tb];
            float4 h1 = *(const float4*)&vout[d][tb + 4];
            acc[0] += h0.x * w; acc[1] += h0.y * w;
            acc[2] += h0.z * w; acc[3] += h0.w * w;
            acc[4] += h1.x * w; acc[5] += h1.y * w;
            acc[6] += h1.z * w; acc[7] += h1.w * w;
        }
        #pragma unroll
        for (int i = 0; i < 8; i++) hid[j][tb + i] = silu(acc[i]);
        __syncthreads();
        if (tid < 128) {
            int hh = tid >> 4, tt = tid & 15;
            float s = xmb2[hh];
            for (int d = 0; d < 128; d++)
                s += hid[d][tt] * xmw2[d * 8 + hh];
            vx[hh][tt] = s;
        }
        __syncthreads();
    }

    // V' cols 16..19: [v_x, v_x*x_c]; 8h * 4c * 16t = 512 writes
    #pragma unroll
    for (int r = 0; r < 2; r++) {
        int i = tid + r * 256;
        int hh = i >> 6, c = (i >> 4) & 3, tt = i & 15;
        float val = vx[hh][tt];
        if (c)
            val *= x[((size_t)(b * 3 + (c - 1))) * 2048 + t0 + tt];
        vT_bf[(((size_t)(b * 8 + hh)) * 32 + 16 + c) * 2048 + t0 + tt] =
            f2b(val);
    }
    // zero-pad cols 20..31: 8h * 12c, 16 t each = 2 x 16B per (hh,c)
    if (tid < 96) {
        int hh = tid / 12, c = 20 + tid % 12;
        s16x8 z = {0,0,0,0,0,0,0,0};
        unsigned short* dst =
            vT_bf + (((size_t)(b * 8 + hh)) * 32 + c) * 2048 + t0;
        *(s16x8*)dst = z;
        *(s16x8*)(dst + 8) = z;
    }
}

// ---------------------------------------------------------------------------
// Kernel 2: MFMA attention (no online softmax; scores bounded).
// One wave per 16-query strip; double-buffered Elds (one barrier per tile).
// Grid: 32 bh * 128 strips = 4096 blocks, 64 threads.
// ---------------------------------------------------------------------------
__global__ __launch_bounds__(64) void attn_mfma(
    const unsigned short* __restrict__ q_bf,
    const unsigned short* __restrict__ k_bf,
    const unsigned short* __restrict__ vT_bf,
    float* __restrict__ o_ws)
{
    const int blk  = blockIdx.x;
    const int bh   = blk >> 7;
    const int qs   = (blk & 127) << 4;
    const int lane = threadIdx.x;
    const int m_   = lane & 15;
    const int quad = lane >> 4;

    __shared__ __align__(16) unsigned short Elds[2][16 * 72];
    __shared__ float Llds[16 * 16];
    __shared__ float Linv[16];

    s16x8 qfrag = {0, 0, 0, 0, 0, 0, 0, 0};
    if (quad < 2)
        qfrag = *(const s16x8*)(q_bf +
                 ((size_t)(bh * 2048 + qs + m_) * 16 + quad * 8));

    f32x4 O0 = {0.f, 0.f, 0.f, 0.f};
    f32x4 O1 = {0.f, 0.f, 0.f, 0.f};
    f32x4 lsum = {0.f, 0.f, 0.f, 0.f};
    const f32x4 zero = {0.f, 0.f, 0.f, 0.f};

    const unsigned short* kb = k_bf  + (size_t)bh * 2048 * 16;
    const unsigned short* vb = vT_bf + (size_t)bh * 32 * 2048;

    for (int kt = 0; kt < 32; kt++) {
        const int k0 = kt * 64;
        const int buf = kt & 1;

        // QK^T: E[n] covers keys k0+16n..+15 (C: row=query, col=key)
        f32x4 E[4];
        #pragma unroll
        for (int n = 0; n < 4; n++) {
            s16x8 kf = {0, 0, 0, 0, 0, 0, 0, 0};
            if (quad < 2)
                kf = *(const s16x8*)(kb +
                      ((size_t)(k0 + n * 16 + m_) * 16 + quad * 8));
            E[n] = __builtin_amdgcn_mfma_f32_16x16x32_bf16(qfrag, kf, zero,
                                                           0, 0, 0);
        }

        // exp, row-sum partials, E (bf16) -> LDS in [query][key] order
        #pragma unroll
        for (int n = 0; n < 4; n++) {
            #pragma unroll
            for (int i = 0; i < 4; i++) {
                float e = __expf(E[n][i]);
                lsum[i] += e;
                Elds[buf][(quad * 4 + i) * 72 + n * 16 + m_] = f2b(e);
            }
        }
        __syncthreads();   // drain writes before reads (single wave)

        // PV: A = E chunk [16q x 32k], B = V' [32k x 16n] (two col-halves)
        #pragma unroll
        for (int c = 0; c < 2; c++) {
            s16x8 af = *(const s16x8*)(&Elds[buf][0] + m_ * 72 + c * 32 + quad * 8);
            s16x8 b0 = *(const s16x8*)(vb + (size_t)m_ * 2048
                                          + k0 + c * 32 + quad * 8);
            s16x8 b1 = *(const s16x8*)(vb + (size_t)(16 + m_) * 2048
                                          + k0 + c * 32 + quad * 8);
            O0 = __builtin_amdgcn_mfma_f32_16x16x32_bf16(af, b0, O0, 0, 0, 0);
            O1 = __builtin_amdgcn_mfma_f32_16x16x32_bf16(af, b1, O1, 0, 0, 0);
        }
        // no trailing barrier: next tile writes the other Elds buffer
    }

    #pragma unroll
    for (int i = 0; i < 4; i++)
        Llds[(quad * 4 + i) * 16 + m_] = lsum[i];
    __syncthreads();
    if (lane < 16) {
        float s = 0.f;
        #pragma unroll
        for (int c2 = 0; c2 < 16; c2++) s += Llds[lane * 16 + c2];
        Linv[lane] = 1.f / s;
    }
    __syncthreads();

    #pragma unroll
    for (int i = 0; i < 4; i++) {
        int row = quad * 4 + i;
        float li = Linv[row];
        float* ob = o_ws + ((size_t)bh * 2048 + qs + row) * 20;
        ob[m_] = O0[i] * li;
        if (m_ < 4) ob[16 + m_] = O1[i] * li;
    }
}

// ---------------------------------------------------------------------------
// Kernel 3: epilogue. 16 tokens per block, 256 threads. Grid: 512. fp32 out.
// h_out = h + (O @ ho_w + ho_b); x_out = x + GVP.
// ---------------------------------------------------------------------------
__global__ __launch_bounds__(256) void epi_kernel(
    const float* __restrict__ o_ws,
    const float* __restrict__ x, const float* __restrict__ hin,
    const float* __restrict__ how, const float* __restrict__ hob,
    const float* __restrict__ Wh, const float* __restrict__ Wu,
    float* __restrict__ out)
{
    const int blk = blockIdx.x;
    const int b  = blk >> 7;
    const int t0 = (blk & 127) << 4;
    const int tid = threadIdx.x;

    __shared__ __align__(16) float hv[128][20];
    __shared__ float gamma[8][16], wx[8][3][16];
    __shared__ float weff[8];

    #pragma unroll
    for (int r = 0; r < 8; r++) {
        int i = tid + r * 256;          // 0..2047
        int jj = i >> 4, tt = i & 15;
        hv[jj][tt] =
            o_ws[(((size_t)b * 8 + (jj >> 4)) * 2048 + t0 + tt) * 20 + (jj & 15)];
    }
    #pragma unroll
    for (int r = 0; r < 2; r++) {
        int i = tid + r * 256;          // 0..511
        int hh = i >> 6, c = (i >> 4) & 3, tt = i & 15;
        float v = o_ws[(((size_t)b * 8 + hh) * 2048 + t0 + tt) * 20 + 16 + c];
        if (c == 0) gamma[hh][tt] = v; else wx[hh][c - 1][tt] = v;
    }
    if (tid < 8) {
        float s = 0.f;
        for (int j = 0; j < 8; j++) s += Wh[tid * 8 + j] * Wu[j];
        weff[tid] = s;
    }
    __syncthreads();

    // h projection: thread owns out-dim d = tid for 16 tokens
    f32x4 a0 = {0,0,0,0}, a1 = {0,0,0,0}, a2 = {0,0,0,0}, a3 = {0,0,0,0};
    for (int jj = 0; jj < 128; jj++) {
        float w = how[jj * 256 + tid];
        float4 v0 = *(const float4*)&hv[jj][0];
        float4 v1 = *(const float4*)&hv[jj][4];
        float4 v2 = *(const float4*)&hv[jj][8];
        float4 v3 = *(const float4*)&hv[jj][12];
        a0[0] += v0.x * w; a0[1] += v0.y * w; a0[2] += v0.z * w; a0[3] += v0.w * w;
        a1[0] += v1.x * w; a1[1] += v1.y * w; a1[2] += v1.z * w; a1[3] += v1.w * w;
        a2[0] += v2.x * w; a2[1] += v2.y * w; a2[2] += v2.z * w; a2[3] += v2.w * w;
        a3[0] += v3.x * w; a3[1] += v3.y * w; a3[2] += v3.z * w; a3[3] += v3.w * w;
    }
    float bias = hob[tid];
    size_t hbase = ((size_t)b * 256 + tid) * 2048 + t0;
    f32x4 accs[4] = {a0, a1, a2, a3};
    #pragma unroll
    for (int g = 0; g < 4; g++) {
        float4 hold = *(const float4*)(hin + hbase + g * 4);
        float4 hres;
        hres.x = hold.x + accs[g][0] + bias;
        hres.y = hold.y + accs[g][1] + bias;
        hres.z = hold.z + accs[g][2] + bias;
        hres.w = hold.w + accs[g][3] + bias;
        *(float4*)(out + 24576 + hbase + g * 4) = hres;
    }

    // GVP / x_out: one thread per token
    if (tid < 16) {
        int tt = tid;
        int t = t0 + tt;
        float Vu[3], xv[3];
        #pragma unroll
        for (int c = 0; c < 3; c++) {
            xv[c] = x[((size_t)b * 3 + c) * 2048 + t];
            float s = 0.f;
            #pragma unroll
            for (int v = 0; v < 8; v++)
                s += (gamma[v][tt] * xv[c] - wx[v][c][tt]) * weff[v];
            Vu[c] = s;
        }
        float gate = sqrtf(Vu[0]*Vu[0] + Vu[1]*Vu[1] + Vu[2]*Vu[2]);
        float sg = 1.f / (1.f + __expf(-gate));
        #pragma unroll
        for (int c = 0; c < 3; c++)
            out[((size_t)b * 3 + c) * 2048 + t] = xv[c] + sg * Vu[c];
    }
}

// ---------------------------------------------------------------------------
extern "C" void kernel_launch(void* const* d_in, const int* in_sizes, int n_in,
                              void* d_out, int out_size, void* d_ws,
                              size_t ws_size, hipStream_t stream)
{
    const float* x    = (const float*)d_in[0];
    const float* h    = (const float*)d_in[1];
    const float* qw1  = (const float*)d_in[2];
    const float* qb1  = (const float*)d_in[3];
    const float* qw2  = (const float*)d_in[4];
    const float* qb2  = (const float*)d_in[5];
    const float* kw1  = (const float*)d_in[6];
    const float* kb1  = (const float*)d_in[7];
    const float* kw2  = (const float*)d_in[8];
    const float* kb2  = (const float*)d_in[9];
    const float* vw1  = (const float*)d_in[10];
    const float* vb1  = (const float*)d_in[11];
    const float* vw2  = (const float*)d_in[12];
    const float* vb2  = (const float*)d_in[13];
    const float* xmw1 = (const float*)d_in[14];
    const float* xmb1 = (const float*)d_in[15];
    const float* xmw2 = (const float*)d_in[16];
    const float* xmb2 = (const float*)d_in[17];
    const float* how  = (const float*)d_in[18];
    const float* hob  = (const float*)d_in[19];
    const float* Wh   = (const float*)d_in[20];
    const float* Wu   = (const float*)d_in[21];
    float* out = (float*)d_out;

    unsigned short* q_bf  = (unsigned short*)d_ws;          // 32*2048*16
    unsigned short* k_bf  = q_bf + (size_t)32 * 2048 * 16;  // 32*2048*16
    unsigned short* vT_bf = k_bf + (size_t)32 * 2048 * 16;  // 32*32*2048
    float* o_ws = (float*)(vT_bf + (size_t)32 * 32 * 2048); // 32*2048*20 fp32

    qkv_kernel<<<512, 256, 0, stream>>>(
        x, h, qw1, qb1, qw2, qb2, kw1, kb1, kw2, kb2,
        vw1, vb1, vw2, vb2, xmw1, xmb1, xmw2, xmb2,
        q_bf, k_bf, vT_bf);
    attn_mfma<<<4096, 64, 0, stream>>>(q_bf, k_bf, vT_bf, o_ws);
    epi_kernel<<<512, 256, 0, stream>>>(o_ws, x, h, how, hob, Wh, Wu, out);
}

// Round 9
// 244.429 us; speedup vs baseline: 2.5588x; 1.1582x over previous
//
#include <hip/hip_runtime.h>
#include <hip/hip_bf16.h>
#include <math.h>

typedef __attribute__((ext_vector_type(8))) short s16x8;   // 8 bf16
typedef __attribute__((ext_vector_type(4))) float f32x4;

__device__ __forceinline__ float silu(float a) {
    return a / (1.f + __expf(-a));
}
__device__ __forceinline__ unsigned short f2b(float f) {
    __hip_bfloat16 h = __float2bfloat16(f);
    return *reinterpret_cast<unsigned short*>(&h);
}

// ---------------------------------------------------------------------------
// Kernel 0: weight prep. Convert MLP weights to bf16, transposed to MFMA
// B-fragment layout [n][k]. w1T: 3 x [128][256] (q,k,v); w2T: 3 x [128][128];
// xm1T: [128][128]; xm2T: [16][128] (cols 8..15 zero).
// ---------------------------------------------------------------------------
__global__ __launch_bounds__(256) void wprep(
    const float* __restrict__ qw1, const float* __restrict__ kw1,
    const float* __restrict__ vw1, const float* __restrict__ qw2,
    const float* __restrict__ kw2, const float* __restrict__ vw2,
    const float* __restrict__ xmw1, const float* __restrict__ xmw2,
    unsigned short* __restrict__ w1T, unsigned short* __restrict__ w2T,
    unsigned short* __restrict__ xm1T, unsigned short* __restrict__ xm2T)
{
    int idx = blockIdx.x * 256 + threadIdx.x;
    if (idx < 98304) {                       // w1T: 3 * 128 * 256
        int m = idx >> 15, r = idx & 32767;
        int n = r >> 8, k = r & 255;
        const float* src = (m == 0) ? qw1 : (m == 1) ? kw1 : vw1;
        w1T[idx] = f2b(src[k * 128 + n]);
    } else if (idx < 147456) {               // w2T: 3 * 128 * 128
        int r0 = idx - 98304;
        int m = r0 >> 14, r = r0 & 16383;
        int n = r >> 7, k = r & 127;
        const float* src = (m == 0) ? qw2 : (m == 1) ? kw2 : vw2;
        w2T[r0] = f2b(src[k * 128 + n]);
    } else if (idx < 163840) {               // xm1T: 128 * 128
        int r = idx - 147456;
        int n = r >> 7, k = r & 127;
        xm1T[r] = f2b(xmw1[k * 128 + n]);
    } else if (idx < 165888) {               // xm2T: 16 * 128
        int r = idx - 163840;
        int n = r >> 7, k = r & 127;
        xm2T[r] = (n < 8) ? f2b(xmw2[k * 8 + n]) : (unsigned short)0;
    }
}

// ---------------------------------------------------------------------------
// Kernel 1: MFMA qkv. 16 tokens per block, 256 threads = 4 waves; wave w owns
// output cols w*32..w*32+31 (2 n-tiles). Grid: B*T/16 = 512 blocks.
// Layer1: [16tok x 256] @ W1 -> silu -> Layer2: @ W2 (K=128). RoPE via
// shfl_xor. v feeds xm MLP (2 more MFMA stages). Outputs bf16:
// q_bf [bh][t][16] (x0.25), k_bf [bh][t][16], vT_bf [bh][32][t] (pad zeroed).
// ---------------------------------------------------------------------------
__global__ __launch_bounds__(256) void qkv_mfma(
    const float* __restrict__ x, const float* __restrict__ h,
    const float* __restrict__ qb1, const float* __restrict__ qb2,
    const float* __restrict__ kb1, const float* __restrict__ kb2,
    const float* __restrict__ vb1, const float* __restrict__ vb2,
    const float* __restrict__ xmb1, const float* __restrict__ xmb2,
    const unsigned short* __restrict__ w1T, const unsigned short* __restrict__ w2T,
    const unsigned short* __restrict__ xm1T, const unsigned short* __restrict__ xm2T,
    unsigned short* __restrict__ q_bf, unsigned short* __restrict__ k_bf,
    unsigned short* __restrict__ vT_bf)
{
    const int blk = blockIdx.x;
    const int b   = blk >> 7;               // 128 blocks per batch
    const int t0  = (blk & 127) << 4;
    const int tid = threadIdx.x;
    const int nq   = tid >> 6;              // wave id = col quarter
    const int lane = tid & 63;
    const int m_   = lane & 15;
    const int quad = lane >> 4;

    __shared__ __align__(16) unsigned short hA[16][264];    // A frags, K=256
    __shared__ __align__(16) unsigned short hidA[16][136];  // hidden, K=128
    __shared__ __align__(16) unsigned short voutA[16][136]; // v out (xm input)
    __shared__ float vxs[16][8];

    // ---- stage h[b][d][t0..t0+15] -> hA[t][d] bf16 (thread = d) ----
    #pragma unroll
    for (int g = 0; g < 4; g++) {
        float4 hv = *(const float4*)(h + ((size_t)(b * 256 + tid)) * 2048
                                       + t0 + g * 4);
        hA[g * 4 + 0][tid] = f2b(hv.x);
        hA[g * 4 + 1][tid] = f2b(hv.y);
        hA[g * 4 + 2][tid] = f2b(hv.z);
        hA[g * 4 + 3][tid] = f2b(hv.w);
    }
    __syncthreads();

    // layer1: K=256, writes silu -> hidA
    auto gemm1 = [&](const unsigned short* w1m, const float* b1) {
        f32x4 acc[2] = {{0.f,0.f,0.f,0.f},{0.f,0.f,0.f,0.f}};
        #pragma unroll
        for (int kc = 0; kc < 8; kc++) {
            s16x8 af = *(const s16x8*)&hA[m_][kc * 32 + quad * 8];
            #pragma unroll
            for (int nt = 0; nt < 2; nt++) {
                const s16x8 bf = *(const s16x8*)(w1m
                    + (size_t)(nq * 32 + nt * 16 + m_) * 256 + kc * 32 + quad * 8);
                acc[nt] = __builtin_amdgcn_mfma_f32_16x16x32_bf16(
                    af, bf, acc[nt], 0, 0, 0);
            }
        }
        #pragma unroll
        for (int nt = 0; nt < 2; nt++) {
            int col = nq * 32 + nt * 16 + m_;
            float bia = b1[col];
            #pragma unroll
            for (int i = 0; i < 4; i++)
                hidA[quad * 4 + i][col] = f2b(silu(acc[nt][i] + bia));
        }
    };
    // layer2: K=128 from hidA (bias added by caller)
    auto gemm2 = [&](const unsigned short* w2m, f32x4 acc[2]) {
        #pragma unroll
        for (int kc = 0; kc < 4; kc++) {
            s16x8 af = *(const s16x8*)&hidA[m_][kc * 32 + quad * 8];
            #pragma unroll
            for (int nt = 0; nt < 2; nt++) {
                const s16x8 bf = *(const s16x8*)(w2m
                    + (size_t)(nq * 32 + nt * 16 + m_) * 128 + kc * 32 + quad * 8);
                acc[nt] = __builtin_amdgcn_mfma_f32_16x16x32_bf16(
                    af, bf, acc[nt], 0, 0, 0);
            }
        }
    };

    // rope + store for q/k (scale: 0.25 for q, 1 for k)
    auto rope_store = [&](f32x4 acc[2], const float* b2,
                          unsigned short* dst, float scale) {
        #pragma unroll
        for (int nt = 0; nt < 2; nt++) {
            int col  = nq * 32 + nt * 16 + m_;
            int head = col >> 4, dim = col & 15;
            float inv = exp2f(-(float)(dim >> 1) * 0.125f * 13.28771238f);
            float bia = b2[col];
            #pragma unroll
            for (int i = 0; i < 4; i++) {
                int t = t0 + quad * 4 + i;
                float a  = acc[nt][i] + bia;
                float pr = __shfl_xor(a, 1);
                float f  = (float)t * inv;
                float cs = cosf(f), sn = sinf(f);
                float o  = (dim & 1) ? (a * cs + pr * sn) : (a * cs - pr * sn);
                dst[((size_t)(b * 8 + head) * 2048 + t) * 16 + dim] =
                    f2b(o * scale);
            }
        }
    };

    // ---- q ----
    gemm1(w1T, qb1);
    __syncthreads();
    {
        f32x4 acc[2] = {{0.f,0.f,0.f,0.f},{0.f,0.f,0.f,0.f}};
        gemm2(w2T, acc);
        rope_store(acc, qb2, q_bf, 0.25f);
    }
    __syncthreads();

    // ---- k ----
    gemm1(w1T + 32768, kb1);
    __syncthreads();
    {
        f32x4 acc[2] = {{0.f,0.f,0.f,0.f},{0.f,0.f,0.f,0.f}};
        gemm2(w2T + 16384, acc);
        rope_store(acc, kb2, k_bf, 1.0f);
    }
    __syncthreads();

    // ---- v ----
    gemm1(w1T + 65536, vb1);
    __syncthreads();
    {
        f32x4 acc[2] = {{0.f,0.f,0.f,0.f},{0.f,0.f,0.f,0.f}};
        gemm2(w2T + 32768, acc);
        #pragma unroll
        for (int nt = 0; nt < 2; nt++) {
            int col = nq * 32 + nt * 16 + m_;
            float bia = vb2[col];
            #pragma unroll
            for (int i = 0; i < 4; i++)
                voutA[quad * 4 + i][col] = f2b(acc[nt][i] + bia);
        }
    }
    __syncthreads();

    // ---- vT store (transpose voutA) + xm layer1 ----
    {
        // 128 cols x 2 token-groups = 256 tasks (1/thread)
        int col = tid >> 1, tg = tid & 1;
        s16x8 pk;
        #pragma unroll
        for (int e = 0; e < 8; e++)
            pk[e] = (short)voutA[tg * 8 + e][col];
        *(s16x8*)(vT_bf + ((size_t)(b * 8 + (col >> 4)) * 32 + (col & 15)) * 2048
                        + t0 + tg * 8) = pk;
    }
    {
        f32x4 acc[2] = {{0.f,0.f,0.f,0.f},{0.f,0.f,0.f,0.f}};
        #pragma unroll
        for (int kc = 0; kc < 4; kc++) {
            s16x8 af = *(const s16x8*)&voutA[m_][kc * 32 + quad * 8];
            #pragma unroll
            for (int nt = 0; nt < 2; nt++) {
                const s16x8 bf = *(const s16x8*)(xm1T
                    + (size_t)(nq * 32 + nt * 16 + m_) * 128 + kc * 32 + quad * 8);
                acc[nt] = __builtin_amdgcn_mfma_f32_16x16x32_bf16(
                    af, bf, acc[nt], 0, 0, 0);
            }
        }
        __syncthreads();   // hidA WAR (v gemm2 reads done)
        #pragma unroll
        for (int nt = 0; nt < 2; nt++) {
            int col = nq * 32 + nt * 16 + m_;
            float bia = xmb1[col];
            #pragma unroll
            for (int i = 0; i < 4; i++)
                hidA[quad * 4 + i][col] = f2b(silu(acc[nt][i] + bia));
        }
    }
    __syncthreads();

    // ---- xm layer2 (wave 0 only; N=16 padded, cols 0..7 real) ----
    if (nq == 0) {
        f32x4 a2 = {0.f, 0.f, 0.f, 0.f};
        #pragma unroll
        for (int kc = 0; kc < 4; kc++) {
            s16x8 af = *(const s16x8*)&hidA[m_][kc * 32 + quad * 8];
            const s16x8 bf = *(const s16x8*)(xm2T
                + (size_t)m_ * 128 + kc * 32 + quad * 8);
            a2 = __builtin_amdgcn_mfma_f32_16x16x32_bf16(af, bf, a2, 0, 0, 0);
        }
        if (m_ < 8) {
            float bia = xmb2[m_];
            #pragma unroll
            for (int i = 0; i < 4; i++)
                vxs[quad * 4 + i][m_] = a2[i] + bia;
        }
    }
    __syncthreads();

    // ---- V' cols 16..19: [v_x, v_x*x_c]; 8h * 4c * 16t = 512 (2/thread) ----
    #pragma unroll
    for (int r = 0; r < 2; r++) {
        int i  = tid + r * 256;
        int hh = i >> 6, c = (i >> 4) & 3, tt = i & 15;
        float val = vxs[tt][hh];
        if (c)
            val *= x[((size_t)(b * 3 + (c - 1))) * 2048 + t0 + tt];
        vT_bf[((size_t)(b * 8 + hh) * 32 + 16 + c) * 2048 + t0 + tt] = f2b(val);
    }
    // zero-pad cols 20..31: 8h * 12c * 2 groups = 192 stores
    if (tid < 192) {
        int hh = tid / 24, rem = tid % 24;
        int c  = 20 + (rem >> 1), tg = rem & 1;
        s16x8 z = {0,0,0,0,0,0,0,0};
        *(s16x8*)(vT_bf + ((size_t)(b * 8 + hh) * 32 + c) * 2048
                        + t0 + tg * 8) = z;
    }
}

// ---------------------------------------------------------------------------
// Kernel 2: MFMA attention (no online softmax; scores bounded).
// One wave per 16-query strip; double-buffered Elds (one barrier per tile).
// Grid: 32 bh * 128 strips = 4096 blocks, 64 threads.
// ---------------------------------------------------------------------------
__global__ __launch_bounds__(64) void attn_mfma(
    const unsigned short* __restrict__ q_bf,
    const unsigned short* __restrict__ k_bf,
    const unsigned short* __restrict__ vT_bf,
    float* __restrict__ o_ws)
{
    const int blk  = blockIdx.x;
    const int bh   = blk >> 7;
    const int qs   = (blk & 127) << 4;
    const int lane = threadIdx.x;
    const int m_   = lane & 15;
    const int quad = lane >> 4;

    __shared__ __align__(16) unsigned short Elds[2][16 * 72];
    __shared__ float Llds[16 * 16];
    __shared__ float Linv[16];

    s16x8 qfrag = {0, 0, 0, 0, 0, 0, 0, 0};
    if (quad < 2)
        qfrag = *(const s16x8*)(q_bf +
                 ((size_t)(bh * 2048 + qs + m_) * 16 + quad * 8));

    f32x4 O0 = {0.f, 0.f, 0.f, 0.f};
    f32x4 O1 = {0.f, 0.f, 0.f, 0.f};
    f32x4 lsum = {0.f, 0.f, 0.f, 0.f};
    const f32x4 zero = {0.f, 0.f, 0.f, 0.f};

    const unsigned short* kb = k_bf  + (size_t)bh * 2048 * 16;
    const unsigned short* vb = vT_bf + (size_t)bh * 32 * 2048;

    for (int kt = 0; kt < 32; kt++) {
        const int k0 = kt * 64;
        const int buf = kt & 1;

        f32x4 E[4];
        #pragma unroll
        for (int n = 0; n < 4; n++) {
            s16x8 kf = {0, 0, 0, 0, 0, 0, 0, 0};
            if (quad < 2)
                kf = *(const s16x8*)(kb +
                      ((size_t)(k0 + n * 16 + m_) * 16 + quad * 8));
            E[n] = __builtin_amdgcn_mfma_f32_16x16x32_bf16(qfrag, kf, zero,
                                                           0, 0, 0);
        }

        #pragma unroll
        for (int n = 0; n < 4; n++) {
            #pragma unroll
            for (int i = 0; i < 4; i++) {
                float e = __expf(E[n][i]);
                lsum[i] += e;
                Elds[buf][(quad * 4 + i) * 72 + n * 16 + m_] = f2b(e);
            }
        }
        __syncthreads();

        #pragma unroll
        for (int c = 0; c < 2; c++) {
            s16x8 af = *(const s16x8*)(&Elds[buf][0] + m_ * 72 + c * 32 + quad * 8);
            s16x8 b0 = *(const s16x8*)(vb + (size_t)m_ * 2048
                                          + k0 + c * 32 + quad * 8);
            s16x8 b1 = *(const s16x8*)(vb + (size_t)(16 + m_) * 2048
                                          + k0 + c * 32 + quad * 8);
            O0 = __builtin_amdgcn_mfma_f32_16x16x32_bf16(af, b0, O0, 0, 0, 0);
            O1 = __builtin_amdgcn_mfma_f32_16x16x32_bf16(af, b1, O1, 0, 0, 0);
        }
    }

    #pragma unroll
    for (int i = 0; i < 4; i++)
        Llds[(quad * 4 + i) * 16 + m_] = lsum[i];
    __syncthreads();
    if (lane < 16) {
        float s = 0.f;
        #pragma unroll
        for (int c2 = 0; c2 < 16; c2++) s += Llds[lane * 16 + c2];
        Linv[lane] = 1.f / s;
    }
    __syncthreads();

    #pragma unroll
    for (int i = 0; i < 4; i++) {
        int row = quad * 4 + i;
        float li = Linv[row];
        float* ob = o_ws + ((size_t)bh * 2048 + qs + row) * 20;
        ob[m_] = O0[i] * li;
        if (m_ < 4) ob[16 + m_] = O1[i] * li;
    }
}

// ---------------------------------------------------------------------------
// Kernel 3: epilogue. 16 tokens per block, 256 threads. Grid: 512. fp32 out.
// h_out = h + (O @ ho_w + ho_b); x_out = x + GVP.
// ---------------------------------------------------------------------------
__global__ __launch_bounds__(256) void epi_kernel(
    const float* __restrict__ o_ws,
    const float* __restrict__ x, const float* __restrict__ hin,
    const float* __restrict__ how, const float* __restrict__ hob,
    const float* __restrict__ Wh, const float* __restrict__ Wu,
    float* __restrict__ out)
{
    const int blk = blockIdx.x;
    const int b  = blk >> 7;
    const int t0 = (blk & 127) << 4;
    const int tid = threadIdx.x;

    __shared__ __align__(16) float hv[128][20];
    __shared__ float gamma[8][16], wx[8][3][16];
    __shared__ float weff[8];

    #pragma unroll
    for (int r = 0; r < 8; r++) {
        int i = tid + r * 256;
        int jj = i >> 4, tt = i & 15;
        hv[jj][tt] =
            o_ws[(((size_t)b * 8 + (jj >> 4)) * 2048 + t0 + tt) * 20 + (jj & 15)];
    }
    #pragma unroll
    for (int r = 0; r < 2; r++) {
        int i = tid + r * 256;
        int hh = i >> 6, c = (i >> 4) & 3, tt = i & 15;
        float v = o_ws[(((size_t)b * 8 + hh) * 2048 + t0 + tt) * 20 + 16 + c];
        if (c == 0) gamma[hh][tt] = v; else wx[hh][c - 1][tt] = v;
    }
    if (tid < 8) {
        float s = 0.f;
        for (int j = 0; j < 8; j++) s += Wh[tid * 8 + j] * Wu[j];
        weff[tid] = s;
    }
    __syncthreads();

    f32x4 a0 = {0,0,0,0}, a1 = {0,0,0,0}, a2 = {0,0,0,0}, a3 = {0,0,0,0};
    for (int jj = 0; jj < 128; jj++) {
        float w = how[jj * 256 + tid];
        float4 v0 = *(const float4*)&hv[jj][0];
        float4 v1 = *(const float4*)&hv[jj][4];
        float4 v2 = *(const float4*)&hv[jj][8];
        float4 v3 = *(const float4*)&hv[jj][12];
        a0[0] += v0.x * w; a0[1] += v0.y * w; a0[2] += v0.z * w; a0[3] += v0.w * w;
        a1[0] += v1.x * w; a1[1] += v1.y * w; a1[2] += v1.z * w; a1[3] += v1.w * w;
        a2[0] += v2.x * w; a2[1] += v2.y * w; a2[2] += v2.z * w; a2[3] += v2.w * w;
        a3[0] += v3.x * w; a3[1] += v3.y * w; a3[2] += v3.z * w; a3[3] += v3.w * w;
    }
    float bias = hob[tid];
    size_t hbase = ((size_t)b * 256 + tid) * 2048 + t0;
    f32x4 accs[4] = {a0, a1, a2, a3};
    #pragma unroll
    for (int g = 0; g < 4; g++) {
        float4 hold = *(const float4*)(hin + hbase + g * 4);
        float4 hres;
        hres.x = hold.x + accs[g][0] + bias;
        hres.y = hold.y + accs[g][1] + bias;
        hres.z = hold.z + accs[g][2] + bias;
        hres.w = hold.w + accs[g][3] + bias;
        *(float4*)(out + 24576 + hbase + g * 4) = hres;
    }

    if (tid < 16) {
        int tt = tid;
        int t = t0 + tt;
        float Vu[3], xv[3];
        #pragma unroll
        for (int c = 0; c < 3; c++) {
            xv[c] = x[((size_t)b * 3 + c) * 2048 + t];
            float s = 0.f;
            #pragma unroll
            for (int v = 0; v < 8; v++)
                s += (gamma[v][tt] * xv[c] - wx[v][c][tt]) * weff[v];
            Vu[c] = s;
        }
        float gate = sqrtf(Vu[0]*Vu[0] + Vu[1]*Vu[1] + Vu[2]*Vu[2]);
        float sg = 1.f / (1.f + __expf(-gate));
        #pragma unroll
        for (int c = 0; c < 3; c++)
            out[((size_t)b * 3 + c) * 2048 + t] = xv[c] + sg * Vu[c];
    }
}

// ---------------------------------------------------------------------------
extern "C" void kernel_launch(void* const* d_in, const int* in_sizes, int n_in,
                              void* d_out, int out_size, void* d_ws,
                              size_t ws_size, hipStream_t stream)
{
    const float* x    = (const float*)d_in[0];
    const float* h    = (const float*)d_in[1];
    const float* qw1  = (const float*)d_in[2];
    const float* qb1  = (const float*)d_in[3];
    const float* qw2  = (const float*)d_in[4];
    const float* qb2  = (const float*)d_in[5];
    const float* kw1  = (const float*)d_in[6];
    const float* kb1  = (const float*)d_in[7];
    const float* kw2  = (const float*)d_in[8];
    const float* kb2  = (const float*)d_in[9];
    const float* vw1  = (const float*)d_in[10];
    const float* vb1  = (const float*)d_in[11];
    const float* vw2  = (const float*)d_in[12];
    const float* vb2  = (const float*)d_in[13];
    const float* xmw1 = (const float*)d_in[14];
    const float* xmb1 = (const float*)d_in[15];
    const float* xmw2 = (const float*)d_in[16];
    const float* xmb2 = (const float*)d_in[17];
    const float* how  = (const float*)d_in[18];
    const float* hob  = (const float*)d_in[19];
    const float* Wh   = (const float*)d_in[20];
    const float* Wu   = (const float*)d_in[21];
    float* out = (float*)d_out;

    unsigned short* q_bf  = (unsigned short*)d_ws;          // 32*2048*16
    unsigned short* k_bf  = q_bf + (size_t)32 * 2048 * 16;  // 32*2048*16
    unsigned short* vT_bf = k_bf + (size_t)32 * 2048 * 16;  // 32*32*2048
    float* o_ws = (float*)(vT_bf + (size_t)32 * 32 * 2048); // 32*2048*20 fp32
    unsigned short* w1T  = (unsigned short*)(o_ws + (size_t)32 * 2048 * 20);
    unsigned short* w2T  = w1T + 98304;
    unsigned short* xm1T = w2T + 49152;
    unsigned short* xm2T = xm1T + 16384;

    wprep<<<648, 256, 0, stream>>>(qw1, kw1, vw1, qw2, kw2, vw2, xmw1, xmw2,
                                   w1T, w2T, xm1T, xm2T);
    qkv_mfma<<<512, 256, 0, stream>>>(
        x, h, qb1, qb2, kb1, kb2, vb1, vb2, xmb1, xmb2,
        w1T, w2T, xm1T, xm2T, q_bf, k_bf, vT_bf);
    attn_mfma<<<4096, 64, 0, stream>>>(q_bf, k_bf, vT_bf, o_ws);
    epi_kernel<<<512, 256, 0, stream>>>(o_ws, x, h, how, hob, Wh, Wu, out);
}

// Round 10
// 241.028 us; speedup vs baseline: 2.5949x; 1.0141x over previous
//
#include <hip/hip_runtime.h>
#include <hip/hip_bf16.h>
#include <math.h>

typedef __attribute__((ext_vector_type(8))) short s16x8;   // 8 bf16
typedef __attribute__((ext_vector_type(4))) float f32x4;

__device__ __forceinline__ float silu(float a) {
    return a / (1.f + __expf(-a));
}
__device__ __forceinline__ unsigned short f2b(float f) {
    __hip_bfloat16 h = __float2bfloat16(f);
    return *reinterpret_cast<unsigned short*>(&h);
}

// ---------------------------------------------------------------------------
// Kernel 0: weight prep (unchanged from r9). bf16 B-layout weights.
// ---------------------------------------------------------------------------
__global__ __launch_bounds__(256) void wprep(
    const float* __restrict__ qw1, const float* __restrict__ kw1,
    const float* __restrict__ vw1, const float* __restrict__ qw2,
    const float* __restrict__ kw2, const float* __restrict__ vw2,
    const float* __restrict__ xmw1, const float* __restrict__ xmw2,
    unsigned short* __restrict__ w1T, unsigned short* __restrict__ w2T,
    unsigned short* __restrict__ xm1T, unsigned short* __restrict__ xm2T)
{
    int idx = blockIdx.x * 256 + threadIdx.x;
    if (idx < 98304) {                       // w1T: 3 * 128 * 256
        int m = idx >> 15, r = idx & 32767;
        int n = r >> 8, k = r & 255;
        const float* src = (m == 0) ? qw1 : (m == 1) ? kw1 : vw1;
        w1T[idx] = f2b(src[k * 128 + n]);
    } else if (idx < 147456) {               // w2T: 3 * 128 * 128
        int r0 = idx - 98304;
        int m = r0 >> 14, r = r0 & 16383;
        int n = r >> 7, k = r & 127;
        const float* src = (m == 0) ? qw2 : (m == 1) ? kw2 : vw2;
        w2T[r0] = f2b(src[k * 128 + n]);
    } else if (idx < 163840) {               // xm1T: 128 * 128
        int r = idx - 147456;
        int n = r >> 7, k = r & 127;
        xm1T[r] = f2b(xmw1[k * 128 + n]);
    } else if (idx < 165888) {               // xm2T: 16 * 128
        int r = idx - 163840;
        int n = r >> 7, k = r & 127;
        xm2T[r] = (n < 8) ? f2b(xmw2[k * 8 + n]) : (unsigned short)0;
    }
}

// ---------------------------------------------------------------------------
// Kernel 1: MFMA qkv (unchanged from r9). 16 tokens/block, 4 waves.
// ---------------------------------------------------------------------------
__global__ __launch_bounds__(256) void qkv_mfma(
    const float* __restrict__ x, const float* __restrict__ h,
    const float* __restrict__ qb1, const float* __restrict__ qb2,
    const float* __restrict__ kb1, const float* __restrict__ kb2,
    const float* __restrict__ vb1, const float* __restrict__ vb2,
    const float* __restrict__ xmb1, const float* __restrict__ xmb2,
    const unsigned short* __restrict__ w1T, const unsigned short* __restrict__ w2T,
    const unsigned short* __restrict__ xm1T, const unsigned short* __restrict__ xm2T,
    unsigned short* __restrict__ q_bf, unsigned short* __restrict__ k_bf,
    unsigned short* __restrict__ vT_bf)
{
    const int blk = blockIdx.x;
    const int b   = blk >> 7;
    const int t0  = (blk & 127) << 4;
    const int tid = threadIdx.x;
    const int nq   = tid >> 6;
    const int lane = tid & 63;
    const int m_   = lane & 15;
    const int quad = lane >> 4;

    __shared__ __align__(16) unsigned short hA[16][264];
    __shared__ __align__(16) unsigned short hidA[16][136];
    __shared__ __align__(16) unsigned short voutA[16][136];
    __shared__ float vxs[16][8];

    #pragma unroll
    for (int g = 0; g < 4; g++) {
        float4 hv = *(const float4*)(h + ((size_t)(b * 256 + tid)) * 2048
                                       + t0 + g * 4);
        hA[g * 4 + 0][tid] = f2b(hv.x);
        hA[g * 4 + 1][tid] = f2b(hv.y);
        hA[g * 4 + 2][tid] = f2b(hv.z);
        hA[g * 4 + 3][tid] = f2b(hv.w);
    }
    __syncthreads();

    auto gemm1 = [&](const unsigned short* w1m, const float* b1) {
        f32x4 acc[2] = {{0.f,0.f,0.f,0.f},{0.f,0.f,0.f,0.f}};
        #pragma unroll
        for (int kc = 0; kc < 8; kc++) {
            s16x8 af = *(const s16x8*)&hA[m_][kc * 32 + quad * 8];
            #pragma unroll
            for (int nt = 0; nt < 2; nt++) {
                const s16x8 bf = *(const s16x8*)(w1m
                    + (size_t)(nq * 32 + nt * 16 + m_) * 256 + kc * 32 + quad * 8);
                acc[nt] = __builtin_amdgcn_mfma_f32_16x16x32_bf16(
                    af, bf, acc[nt], 0, 0, 0);
            }
        }
        #pragma unroll
        for (int nt = 0; nt < 2; nt++) {
            int col = nq * 32 + nt * 16 + m_;
            float bia = b1[col];
            #pragma unroll
            for (int i = 0; i < 4; i++)
                hidA[quad * 4 + i][col] = f2b(silu(acc[nt][i] + bia));
        }
    };
    auto gemm2 = [&](const unsigned short* w2m, f32x4 acc[2]) {
        #pragma unroll
        for (int kc = 0; kc < 4; kc++) {
            s16x8 af = *(const s16x8*)&hidA[m_][kc * 32 + quad * 8];
            #pragma unroll
            for (int nt = 0; nt < 2; nt++) {
                const s16x8 bf = *(const s16x8*)(w2m
                    + (size_t)(nq * 32 + nt * 16 + m_) * 128 + kc * 32 + quad * 8);
                acc[nt] = __builtin_amdgcn_mfma_f32_16x16x32_bf16(
                    af, bf, acc[nt], 0, 0, 0);
            }
        }
    };
    auto rope_store = [&](f32x4 acc[2], const float* b2,
                          unsigned short* dst, float scale) {
        #pragma unroll
        for (int nt = 0; nt < 2; nt++) {
            int col  = nq * 32 + nt * 16 + m_;
            int head = col >> 4, dim = col & 15;
            float inv = exp2f(-(float)(dim >> 1) * 0.125f * 13.28771238f);
            float bia = b2[col];
            #pragma unroll
            for (int i = 0; i < 4; i++) {
                int t = t0 + quad * 4 + i;
                float a  = acc[nt][i] + bia;
                float pr = __shfl_xor(a, 1);
                float f  = (float)t * inv;
                float cs = cosf(f), sn = sinf(f);
                float o  = (dim & 1) ? (a * cs + pr * sn) : (a * cs - pr * sn);
                dst[((size_t)(b * 8 + head) * 2048 + t) * 16 + dim] =
                    f2b(o * scale);
            }
        }
    };

    gemm1(w1T, qb1);
    __syncthreads();
    {
        f32x4 acc[2] = {{0.f,0.f,0.f,0.f},{0.f,0.f,0.f,0.f}};
        gemm2(w2T, acc);
        rope_store(acc, qb2, q_bf, 0.25f);
    }
    __syncthreads();

    gemm1(w1T + 32768, kb1);
    __syncthreads();
    {
        f32x4 acc[2] = {{0.f,0.f,0.f,0.f},{0.f,0.f,0.f,0.f}};
        gemm2(w2T + 16384, acc);
        rope_store(acc, kb2, k_bf, 1.0f);
    }
    __syncthreads();

    gemm1(w1T + 65536, vb1);
    __syncthreads();
    {
        f32x4 acc[2] = {{0.f,0.f,0.f,0.f},{0.f,0.f,0.f,0.f}};
        gemm2(w2T + 32768, acc);
        #pragma unroll
        for (int nt = 0; nt < 2; nt++) {
            int col = nq * 32 + nt * 16 + m_;
            float bia = vb2[col];
            #pragma unroll
            for (int i = 0; i < 4; i++)
                voutA[quad * 4 + i][col] = f2b(acc[nt][i] + bia);
        }
    }
    __syncthreads();

    {
        int col = tid >> 1, tg = tid & 1;
        s16x8 pk;
        #pragma unroll
        for (int e = 0; e < 8; e++)
            pk[e] = (short)voutA[tg * 8 + e][col];
        *(s16x8*)(vT_bf + ((size_t)(b * 8 + (col >> 4)) * 32 + (col & 15)) * 2048
                        + t0 + tg * 8) = pk;
    }
    {
        f32x4 acc[2] = {{0.f,0.f,0.f,0.f},{0.f,0.f,0.f,0.f}};
        #pragma unroll
        for (int kc = 0; kc < 4; kc++) {
            s16x8 af = *(const s16x8*)&voutA[m_][kc * 32 + quad * 8];
            #pragma unroll
            for (int nt = 0; nt < 2; nt++) {
                const s16x8 bf = *(const s16x8*)(xm1T
                    + (size_t)(nq * 32 + nt * 16 + m_) * 128 + kc * 32 + quad * 8);
                acc[nt] = __builtin_amdgcn_mfma_f32_16x16x32_bf16(
                    af, bf, acc[nt], 0, 0, 0);
            }
        }
        __syncthreads();
        #pragma unroll
        for (int nt = 0; nt < 2; nt++) {
            int col = nq * 32 + nt * 16 + m_;
            float bia = xmb1[col];
            #pragma unroll
            for (int i = 0; i < 4; i++)
                hidA[quad * 4 + i][col] = f2b(silu(acc[nt][i] + bia));
        }
    }
    __syncthreads();

    if (nq == 0) {
        f32x4 a2 = {0.f, 0.f, 0.f, 0.f};
        #pragma unroll
        for (int kc = 0; kc < 4; kc++) {
            s16x8 af = *(const s16x8*)&hidA[m_][kc * 32 + quad * 8];
            const s16x8 bf = *(const s16x8*)(xm2T
                + (size_t)m_ * 128 + kc * 32 + quad * 8);
            a2 = __builtin_amdgcn_mfma_f32_16x16x32_bf16(af, bf, a2, 0, 0, 0);
        }
        if (m_ < 8) {
            float bia = xmb2[m_];
            #pragma unroll
            for (int i = 0; i < 4; i++)
                vxs[quad * 4 + i][m_] = a2[i] + bia;
        }
    }
    __syncthreads();

    #pragma unroll
    for (int r = 0; r < 2; r++) {
        int i  = tid + r * 256;
        int hh = i >> 6, c = (i >> 4) & 3, tt = i & 15;
        float val = vxs[tt][hh];
        if (c)
            val *= x[((size_t)(b * 3 + (c - 1))) * 2048 + t0 + tt];
        vT_bf[((size_t)(b * 8 + hh) * 32 + 16 + c) * 2048 + t0 + tt] = f2b(val);
    }
    if (tid < 192) {
        int hh = tid / 24, rem = tid % 24;
        int c  = 20 + (rem >> 1), tg = rem & 1;
        s16x8 z = {0,0,0,0,0,0,0,0};
        *(s16x8*)(vT_bf + ((size_t)(b * 8 + hh) * 32 + c) * 2048
                        + t0 + tg * 8) = z;
    }
}

// ---------------------------------------------------------------------------
// Kernel 2: MFMA attention, 2-way key split, S^T operand swap + packed b64
// LDS writes. One wave per (split, 16-query strip). Grid: 2*32*128 = 8192
// single-wave blocks -> 32 waves/CU. Emits UNNORMALIZED O (cols 0..19) and
// row-sum l (col 20) into opart[sp][bh][t][24].
// ---------------------------------------------------------------------------
__global__ __launch_bounds__(64) void attn_mfma(
    const unsigned short* __restrict__ q_bf,
    const unsigned short* __restrict__ k_bf,
    const unsigned short* __restrict__ vT_bf,
    float* __restrict__ opart)
{
    const int blk  = blockIdx.x;
    const int sp   = blk >> 12;              // key split 0/1
    const int bh   = (blk >> 7) & 31;
    const int qs   = (blk & 127) << 4;
    const int lane = threadIdx.x;
    const int m_   = lane & 15;
    const int quad = lane >> 4;

    __shared__ __align__(16) unsigned short Elds[2][16 * 72];

    s16x8 qfrag = {0, 0, 0, 0, 0, 0, 0, 0};
    if (quad < 2)
        qfrag = *(const s16x8*)(q_bf +
                 ((size_t)(bh * 2048 + qs + m_) * 16 + quad * 8));

    f32x4 O0 = {0.f, 0.f, 0.f, 0.f};
    f32x4 O1 = {0.f, 0.f, 0.f, 0.f};
    f32x4 lsum = {0.f, 0.f, 0.f, 0.f};
    const f32x4 zero = {0.f, 0.f, 0.f, 0.f};

    const unsigned short* kb = k_bf + ((size_t)bh * 2048 + sp * 1024) * 16;
    const unsigned short* vb = vT_bf + (size_t)bh * 32 * 2048 + sp * 1024;

    for (int kt = 0; kt < 16; kt++) {        // 16 tiles of 64 keys
        const int k0 = kt * 64;
        const int buf = kt & 1;

        // S^T = K·Q^T: A = K-frag (m=key), B = Q-frag (n=query).
        // C: row = key-in-group (quad*4+i), col = query (m_).
        f32x4 E[4];
        #pragma unroll
        for (int n = 0; n < 4; n++) {
            s16x8 kf = {0, 0, 0, 0, 0, 0, 0, 0};
            if (quad < 2)
                kf = *(const s16x8*)(kb +
                      ((size_t)(k0 + n * 16 + m_) * 16 + quad * 8));
            E[n] = __builtin_amdgcn_mfma_f32_16x16x32_bf16(kf, qfrag, zero,
                                                           0, 0, 0);
        }

        // exp + per-query row-sum (lane m_ owns query m_) + packed E writes:
        // Elds[query][key-in-tile]; lane writes 4 consecutive keys as b64.
        #pragma unroll
        for (int n = 0; n < 4; n++) {
            float e0 = __expf(E[n][0]); lsum[0] += e0;
            float e1 = __expf(E[n][1]); lsum[1] += e1;
            float e2 = __expf(E[n][2]); lsum[2] += e2;
            float e3 = __expf(E[n][3]); lsum[3] += e3;
            uint2 pk;
            pk.x = (unsigned)f2b(e0) | ((unsigned)f2b(e1) << 16);
            pk.y = (unsigned)f2b(e2) | ((unsigned)f2b(e3) << 16);
            *(uint2*)&Elds[buf][m_ * 72 + n * 16 + quad * 4] = pk;
        }
        __syncthreads();

        // PV: A = E [16q x 32k] from LDS, B = V' [32k x 16n] global.
        #pragma unroll
        for (int c = 0; c < 2; c++) {
            s16x8 af = *(const s16x8*)&Elds[buf][m_ * 72 + c * 32 + quad * 8];
            s16x8 b0 = *(const s16x8*)(vb + (size_t)m_ * 2048
                                          + k0 + c * 32 + quad * 8);
            s16x8 b1 = *(const s16x8*)(vb + (size_t)(16 + m_) * 2048
                                          + k0 + c * 32 + quad * 8);
            O0 = __builtin_amdgcn_mfma_f32_16x16x32_bf16(af, b0, O0, 0, 0, 0);
            O1 = __builtin_amdgcn_mfma_f32_16x16x32_bf16(af, b1, O1, 0, 0, 0);
        }
    }

    // l for query m_: sum own 4 + across quads (lanes m_+16q)
    float s = lsum[0] + lsum[1] + lsum[2] + lsum[3];
    s += __shfl_xor(s, 16);
    s += __shfl_xor(s, 32);

    float* opb = opart + ((size_t)(sp * 32 + bh) * 2048 + qs) * 24;
    #pragma unroll
    for (int i = 0; i < 4; i++) {
        int row = quad * 4 + i;              // query row
        float* ob = opb + row * 24;
        ob[m_] = O0[i];
        if (m_ < 4) ob[16 + m_] = O1[i];
    }
    if (quad == 0) opb[m_ * 24 + 20] = s;    // unnormalized l for query m_
}

// ---------------------------------------------------------------------------
// Kernel 3: epilogue. 8 tokens per block, 256 threads. Grid: 1024. fp32 out.
// Combines the 2 key-split partials (plain sums), normalizes, then
// h_out = h + (O @ ho_w + ho_b); x_out = x + GVP.
// ---------------------------------------------------------------------------
__global__ __launch_bounds__(256) void epi_kernel(
    const float* __restrict__ opart,
    const float* __restrict__ x, const float* __restrict__ hin,
    const float* __restrict__ how, const float* __restrict__ hob,
    const float* __restrict__ Wh, const float* __restrict__ Wu,
    float* __restrict__ out)
{
    const int blk = blockIdx.x;
    const int b  = blk >> 8;
    const int t0 = (blk & 255) << 3;
    const int tid = threadIdx.x;
    const size_t half = (size_t)32 * 2048 * 24;

    __shared__ __align__(16) float hv[128][8];
    __shared__ float gamma[8][8], wx[8][3][8];
    __shared__ float linv[8][8];
    __shared__ float weff[8];

    if (tid < 64) {
        int hh = tid >> 3, tt = tid & 7;
        size_t off = ((size_t)(b * 8 + hh) * 2048 + t0 + tt) * 24 + 20;
        linv[hh][tt] = 1.f / (opart[off] + opart[half + off]);
    } else if (tid < 72) {
        int v = tid - 64;
        float s = 0.f;
        for (int j = 0; j < 8; j++) s += Wh[v * 8 + j] * Wu[j];
        weff[v] = s;
    }
    __syncthreads();

    #pragma unroll
    for (int r = 0; r < 4; r++) {
        int i = tid + r * 256;               // 0..1023
        int jj = i >> 3, tt = i & 7;
        size_t off = ((size_t)(b * 8 + (jj >> 4)) * 2048 + t0 + tt) * 24
                   + (jj & 15);
        hv[jj][tt] = (opart[off] + opart[half + off]) * linv[jj >> 4][tt];
    }
    {
        int hh = tid >> 5, c = (tid >> 3) & 3, tt = tid & 7;
        size_t off = ((size_t)(b * 8 + hh) * 2048 + t0 + tt) * 24 + 16 + c;
        float v = (opart[off] + opart[half + off]) * linv[hh][tt];
        if (c == 0) gamma[hh][tt] = v; else wx[hh][c - 1][tt] = v;
    }
    __syncthreads();

    // h projection: thread owns out-dim d = tid for 8 tokens
    f32x4 a0 = {0,0,0,0}, a1 = {0,0,0,0};
    for (int jj = 0; jj < 128; jj++) {
        float w = how[jj * 256 + tid];
        float4 v0 = *(const float4*)&hv[jj][0];
        float4 v1 = *(const float4*)&hv[jj][4];
        a0[0] += v0.x * w; a0[1] += v0.y * w; a0[2] += v0.z * w; a0[3] += v0.w * w;
        a1[0] += v1.x * w; a1[1] += v1.y * w; a1[2] += v1.z * w; a1[3] += v1.w * w;
    }
    float bias = hob[tid];
    size_t hbase = ((size_t)b * 256 + tid) * 2048 + t0;
    f32x4 accs[2] = {a0, a1};
    #pragma unroll
    for (int g = 0; g < 2; g++) {
        float4 hold = *(const float4*)(hin + hbase + g * 4);
        float4 hres;
        hres.x = hold.x + accs[g][0] + bias;
        hres.y = hold.y + accs[g][1] + bias;
        hres.z = hold.z + accs[g][2] + bias;
        hres.w = hold.w + accs[g][3] + bias;
        *(float4*)(out + 24576 + hbase + g * 4) = hres;
    }

    // GVP / x_out: one thread per token
    if (tid < 8) {
        int tt = tid;
        int t = t0 + tt;
        float Vu[3], xv[3];
        #pragma unroll
        for (int c = 0; c < 3; c++) {
            xv[c] = x[((size_t)b * 3 + c) * 2048 + t];
            float s = 0.f;
            #pragma unroll
            for (int v = 0; v < 8; v++)
                s += (gamma[v][tt] * xv[c] - wx[v][c][tt]) * weff[v];
            Vu[c] = s;
        }
        float gate = sqrtf(Vu[0]*Vu[0] + Vu[1]*Vu[1] + Vu[2]*Vu[2]);
        float sg = 1.f / (1.f + __expf(-gate));
        #pragma unroll
        for (int c = 0; c < 3; c++)
            out[((size_t)b * 3 + c) * 2048 + t] = xv[c] + sg * Vu[c];
    }
}

// ---------------------------------------------------------------------------
extern "C" void kernel_launch(void* const* d_in, const int* in_sizes, int n_in,
                              void* d_out, int out_size, void* d_ws,
                              size_t ws_size, hipStream_t stream)
{
    const float* x    = (const float*)d_in[0];
    const float* h    = (const float*)d_in[1];
    const float* qw1  = (const float*)d_in[2];
    const float* qb1  = (const float*)d_in[3];
    const float* qw2  = (const float*)d_in[4];
    const float* qb2  = (const float*)d_in[5];
    const float* kw1  = (const float*)d_in[6];
    const float* kb1  = (const float*)d_in[7];
    const float* kw2  = (const float*)d_in[8];
    const float* kb2  = (const float*)d_in[9];
    const float* vw1  = (const float*)d_in[10];
    const float* vb1  = (const float*)d_in[11];
    const float* vw2  = (const float*)d_in[12];
    const float* vb2  = (const float*)d_in[13];
    const float* xmw1 = (const float*)d_in[14];
    const float* xmb1 = (const float*)d_in[15];
    const float* xmw2 = (const float*)d_in[16];
    const float* xmb2 = (const float*)d_in[17];
    const float* how  = (const float*)d_in[18];
    const float* hob  = (const float*)d_in[19];
    const float* Wh   = (const float*)d_in[20];
    const float* Wu   = (const float*)d_in[21];
    float* out = (float*)d_out;

    unsigned short* q_bf  = (unsigned short*)d_ws;          // 32*2048*16 us
    unsigned short* k_bf  = q_bf + (size_t)32 * 2048 * 16;
    unsigned short* vT_bf = k_bf + (size_t)32 * 2048 * 16;  // 32*32*2048 us
    float* opart = (float*)(vT_bf + (size_t)32 * 32 * 2048); // 2*32*2048*24 f
    unsigned short* w1T  = (unsigned short*)(opart + (size_t)2 * 32 * 2048 * 24);
    unsigned short* w2T  = w1T + 98304;
    unsigned short* xm1T = w2T + 49152;
    unsigned short* xm2T = xm1T + 16384;

    wprep<<<648, 256, 0, stream>>>(qw1, kw1, vw1, qw2, kw2, vw2, xmw1, xmw2,
                                   w1T, w2T, xm1T, xm2T);
    qkv_mfma<<<512, 256, 0, stream>>>(
        x, h, qb1, qb2, kb1, kb2, vb1, vb2, xmb1, xmb2,
        w1T, w2T, xm1T, xm2T, q_bf, k_bf, vT_bf);
    attn_mfma<<<8192, 64, 0, stream>>>(q_bf, k_bf, vT_bf, opart);
    epi_kernel<<<1024, 256, 0, stream>>>(opart, x, h, how, hob, Wh, Wu, out);
}